// Round 1
// baseline (1657.004 us; speedup 1.0000x reference)
//
#include <hip/hip_runtime.h>
#include <stdint.h>

// ---------------- problem constants ----------------
#define N_USERS 100000
#define N_ITEMS 200000
#define NTOT    300000
#define DIM     64
#define NNZ     4000000

// output layout (floats)
#define OUT_I    25600000   // after users embs  (100000*4*64)
#define OUT_CLU  76800000   // after items embs  (+200000*4*64)
#define OUT_CLI  83200000   // after users cl    (+100000*64)

// JAX PRNG mode: 1 = threefry_partitionable (default since jax 0.4.30), 0 = original
#define PARTITIONABLE 1

// ---------------- threefry2x32 (20 rounds) ----------------
__host__ __device__ __forceinline__ void tf2x32(uint32_t k0, uint32_t k1,
                                                uint32_t x0, uint32_t x1,
                                                uint32_t& o0, uint32_t& o1) {
  uint32_t ks2 = k0 ^ k1 ^ 0x1BD11BDAu;
#define TFR(r) { x0 += x1; x1 = (x1 << (r)) | (x1 >> (32 - (r))); x1 ^= x0; }
  x0 += k0; x1 += k1;
  TFR(13) TFR(15) TFR(26) TFR(6)
  x0 += k1;  x1 += ks2 + 1u;
  TFR(17) TFR(29) TFR(16) TFR(24)
  x0 += ks2; x1 += k0 + 2u;
  TFR(13) TFR(15) TFR(26) TFR(6)
  x0 += k0;  x1 += k1 + 3u;
  TFR(17) TFR(29) TFR(16) TFR(24)
  x0 += k1;  x1 += ks2 + 4u;
  TFR(13) TFR(15) TFR(26) TFR(6)
  x0 += ks2; x1 += k0 + 5u;
#undef TFR
  o0 = x0; o1 = x1;
}

// per-element random bits for a flat index j in an array of size `total`
__device__ __forceinline__ uint32_t rnd_bits(uint32_t k0, uint32_t k1, uint32_t j, uint32_t half) {
#if PARTITIONABLE
  (void)half;
  uint32_t a, b;
  tf2x32(k0, k1, 0u, j, a, b);
  return a ^ b;
#else
  uint32_t x0, x1, a, b;
  if (j < half) { x0 = j; x1 = j + half; } else { x0 = j - half; x1 = j; }
  tf2x32(k0, k1, x0, x1, a, b);
  return (j < half) ? a : b;
#endif
}

__device__ __forceinline__ float u01f(uint32_t bits) {
  return __uint_as_float((bits >> 9) | 0x3f800000u) - 1.0f;
}

// ---------------- CSR build ----------------
__global__ void k_hist(const int* __restrict__ rows, int* __restrict__ cnt, int nnz) {
  int e = blockIdx.x * blockDim.x + threadIdx.x;
  if (e < nnz) atomicAdd(&cnt[rows[e]], 1);
}

__global__ void k_scan1(const int* __restrict__ cnt, int* __restrict__ rowstart,
                        int* __restrict__ bsum, int n) {
  __shared__ int sm[256];
  int t = threadIdx.x;
  int base = blockIdx.x * 1024 + t * 4;
  int v0 = (base     < n) ? cnt[base]     : 0;
  int v1 = (base + 1 < n) ? cnt[base + 1] : 0;
  int v2 = (base + 2 < n) ? cnt[base + 2] : 0;
  int v3 = (base + 3 < n) ? cnt[base + 3] : 0;
  int s = v0 + v1 + v2 + v3;
  sm[t] = s;
  __syncthreads();
  for (int off = 1; off < 256; off <<= 1) {
    int y = (t >= off) ? sm[t - off] : 0;
    __syncthreads();
    sm[t] += y;
    __syncthreads();
  }
  int ex = sm[t] - s;
  if (base     < n) rowstart[base]     = ex;
  if (base + 1 < n) rowstart[base + 1] = ex + v0;
  if (base + 2 < n) rowstart[base + 2] = ex + v0 + v1;
  if (base + 3 < n) rowstart[base + 3] = ex + v0 + v1 + v2;
  if (t == 255) bsum[blockIdx.x] = sm[255];
}

__global__ void k_scan2(int* bsum, int nb) {
  __shared__ int sm[512];
  int t = threadIdx.x;
  int v = (t < nb) ? bsum[t] : 0;
  sm[t] = v;
  __syncthreads();
  for (int off = 1; off < 512; off <<= 1) {
    int y = (t >= off) ? sm[t - off] : 0;
    __syncthreads();
    sm[t] += y;
    __syncthreads();
  }
  if (t < nb) bsum[t] = sm[t] - v;  // exclusive block offsets
}

__global__ void k_scan3(int* rowstart, const int* __restrict__ bsum, int* fill, int n) {
  int i = blockIdx.x * blockDim.x + threadIdx.x;
  if (i < n) {
    int s = rowstart[i] + bsum[i >> 10];
    rowstart[i] = s;
    fill[i] = s;
  }
}

__global__ void k_scatter(const int* __restrict__ rows, const int* __restrict__ cols,
                          int* fill, int* cols_s, int* idx_s, int nnz) {
  int e = blockIdx.x * blockDim.x + threadIdx.x;
  if (e < nnz) {
    int r = rows[e];
    int pos = atomicAdd(&fill[r], 1);
    cols_s[pos] = cols[e];
    idx_s[pos]  = e;
  }
}

// deterministic within-row order: sort each row's edges by original edge index
__global__ void k_rowsort(const int* __restrict__ rowstart, const int* __restrict__ cnt,
                          int* cols_s, int* idx_s, int n) {
  int r = blockIdx.x * blockDim.x + threadIdx.x;
  if (r >= n) return;
  int s = rowstart[r], m = cnt[r];
  for (int a = 1; a < m; a++) {
    int ki = idx_s[s + a], kc = cols_s[s + a];
    int b = a - 1;
    while (b >= 0 && idx_s[s + b] > ki) {
      idx_s[s + b + 1] = idx_s[s + b];
      cols_s[s + b + 1] = cols_s[s + b];
      b--;
    }
    idx_s[s + b + 1] = ki;
    cols_s[s + b + 1] = kc;
  }
}

// ---------------- hop 0 init: agg = concat(ue, ie); out slot 0 ----------------
__global__ void k_init(const float* __restrict__ ue, const float* __restrict__ ie,
                       float* __restrict__ agg, float* __restrict__ out) {
  int t = blockIdx.x * blockDim.x + threadIdx.x;
  if (t >= NTOT * DIM / 4) return;
  int j = t * 4;
  int r = j >> 6;
  int d = j & 63;
  float4 v = (r < N_USERS) ? *reinterpret_cast<const float4*>(ue + j)
                           : *reinterpret_cast<const float4*>(ie + (j - N_USERS * DIM));
  *reinterpret_cast<float4*>(agg + j) = v;
  int o = (r < N_USERS) ? (r * 256 + d) : (OUT_I + (r - N_USERS) * 256 + d);
  *reinterpret_cast<float4*>(out + o) = v;
}

// ---------------- per-hop masked edge values (in CSR order) ----------------
__global__ void k_edgeval(const float* __restrict__ adjv, const int* __restrict__ idx_s,
                          float* __restrict__ vals_h, uint32_t ke0, uint32_t ke1, int nnz) {
  int i = blockIdx.x * blockDim.x + threadIdx.x;
  if (i >= nnz) return;
  int e = idx_s[i];
  uint32_t bits = rnd_bits(ke0, ke1, (uint32_t)e, (uint32_t)(NNZ / 2));
  // edge_mask = floor(0.5 + u) = (u >= 0.5) = top bit of mantissa source
  vals_h[i] = (bits & 0x80000000u) ? adjv[e] * 2.0f : 0.0f;
}

// ---------------- SpMM: one 64-lane wave per output row, lane = dim ----------------
__global__ __launch_bounds__(256) void k_spmm(const int* __restrict__ rowstart,
                                              const int* __restrict__ cnt,
                                              const int* __restrict__ cols_s,
                                              const float* __restrict__ vals_h,
                                              const float* __restrict__ X,
                                              float* __restrict__ Y) {
  int gid = blockIdx.x * blockDim.x + threadIdx.x;
  int r = gid >> 6;
  int lane = gid & 63;
  if (r >= NTOT) return;
  int s = rowstart[r], m = cnt[r];
  float acc = 0.0f;
  int k = 0;
  for (; k + 3 < m; k += 4) {
    int c0 = cols_s[s + k], c1 = cols_s[s + k + 1], c2 = cols_s[s + k + 2], c3 = cols_s[s + k + 3];
    float v0 = vals_h[s + k], v1 = vals_h[s + k + 1], v2 = vals_h[s + k + 2], v3 = vals_h[s + k + 3];
    float x0 = X[c0 * DIM + lane];
    float x1 = X[c1 * DIM + lane];
    float x2 = X[c2 * DIM + lane];
    float x3 = X[c3 * DIM + lane];
    acc = fmaf(v0, x0, acc);
    acc = fmaf(v1, x1, acc);
    acc = fmaf(v2, x2, acc);
    acc = fmaf(v3, x3, acc);
  }
  for (; k < m; k++) {
    int c = cols_s[s + k];
    float v = vals_h[s + k];
    acc = fmaf(v, X[c * DIM + lane], acc);
  }
  Y[r * DIM + lane] = acc;
}

// ---------------- post: LN + dropout + normalized-noise perturb + outputs ----------------
__global__ __launch_bounds__(256) void k_post(float* __restrict__ Y,
                                              const float* __restrict__ gamma,
                                              const float* __restrict__ beta,
                                              float* __restrict__ out,
                                              uint32_t km0, uint32_t km1,
                                              uint32_t kp0, uint32_t kp1, int hop) {
  int gid = blockIdx.x * blockDim.x + threadIdx.x;
  int r = gid >> 6;
  int d = gid & 63;
  if (r >= NTOT) return;
  float x = Y[r * DIM + d];

  // layer norm over the 64 lanes of this wave
  float t = x;
#pragma unroll
  for (int m = 32; m >= 1; m >>= 1) t += __shfl_xor(t, m, 64);
  float mu = t * (1.0f / 64.0f);
  float dv = x - mu;
  float t2 = dv * dv;
#pragma unroll
  for (int m = 32; m >= 1; m >>= 1) t2 += __shfl_xor(t2, m, 64);
  float var = t2 * (1.0f / 64.0f);
  x = dv * rsqrtf(var + 1e-5f) * gamma[d] + beta[d];

  // message dropout: keep iff uniform >= 0.1
  uint32_t j = (uint32_t)(r * DIM + d);
  float um = u01f(rnd_bits(km0, km1, j, (uint32_t)(NTOT * DIM / 2)));
  const float INV_KEEP = (float)(1.0 / 0.9);
  x = x * ((um >= 0.1f) ? INV_KEEP : 0.0f);

  // perturbation: normal via erfinv of uniform(lo, 1), row-normalized
  float un = u01f(rnd_bits(kp0, kp1, j, (uint32_t)(NTOT * DIM / 2)));
  const float LO = __uint_as_float(0xBF7FFFFFu);  // nextafter(-1, 0)
  float val = un * 2.0f + LO;                      // scale (1 - lo) rounds to 2.0f
  float nz = 0x1.6a09e6p+0f * erfinvf(val);        // sqrt(2) * erfinv
  float s2 = nz * nz;
#pragma unroll
  for (int m = 32; m >= 1; m >>= 1) s2 += __shfl_xor(s2, m, 64);
  float nrm = sqrtf(s2);
  float nh = nz / (nrm + 1e-12f);
  float sg = (x > 0.0f) ? 1.0f : ((x < 0.0f) ? -1.0f : 0.0f);
  x = x + sg * nh * 0.03f;

  // write back for next hop + outputs
  Y[r * DIM + d] = x;
  int h1 = hop + 1;
  if (r < N_USERS) {
    out[r * 256 + h1 * 64 + d] = x;
    if (hop == 0) out[OUT_CLU + r * 64 + d] = x;
  } else {
    int i = r - N_USERS;
    out[OUT_I + i * 256 + h1 * 64 + d] = x;
    if (hop == 0) out[OUT_CLI + i * 64 + d] = x;
  }
}

// ---------------- launch ----------------
extern "C" void kernel_launch(void* const* d_in, const int* in_sizes, int n_in,
                              void* d_out, int out_size, void* d_ws, size_t ws_size,
                              hipStream_t stream) {
  (void)in_sizes; (void)n_in; (void)out_size; (void)ws_size;
  const float* ue    = (const float*)d_in[0];
  const float* ie    = (const float*)d_in[1];
  const float* adjv  = (const float*)d_in[2];
  const float* gamma = (const float*)d_in[3];
  const float* beta  = (const float*)d_in[4];
  const int*   adji  = (const int*)d_in[5];
  const int* rows = adji;
  const int* cols = adji + NNZ;
  float* out = (float*)d_out;

  char* ws = (char*)d_ws;
  size_t off = 0;
  auto alloc = [&](size_t bytes) -> void* {
    void* p = ws + off;
    off += (bytes + 255) & ~(size_t)255;
    return p;
  };
  float* aggA   = (float*)alloc(sizeof(float) * NTOT * DIM);
  float* aggB   = (float*)alloc(sizeof(float) * NTOT * DIM);
  int*   cnt    = (int*)alloc(sizeof(int) * NTOT);
  int*   rowst  = (int*)alloc(sizeof(int) * NTOT);
  int*   fill   = (int*)alloc(sizeof(int) * NTOT);
  int*   bsum   = (int*)alloc(sizeof(int) * 512);
  int*   cols_s = (int*)alloc(sizeof(int) * NNZ);
  int*   idx_s  = (int*)alloc(sizeof(int) * NNZ);
  float* vals_h = (float*)alloc(sizeof(float) * NNZ);

  // host-side key derivation: kh = fold_in(key(42), hop); (ke,km,kp) = split(kh, 3)
  uint32_t K[3][6];
  for (uint32_t h = 0; h < 3; h++) {
    uint32_t h0, h1;
    tf2x32(0u, 42u, 0u, h, h0, h1);
#if PARTITIONABLE
    tf2x32(h0, h1, 0u, 0u, K[h][0], K[h][1]);  // ke
    tf2x32(h0, h1, 0u, 1u, K[h][2], K[h][3]);  // km
    tf2x32(h0, h1, 0u, 2u, K[h][4], K[h][5]);  // kp
#else
    uint32_t a0, a1, b0, b1, c0, c1;
    tf2x32(h0, h1, 0u, 3u, a0, a1);
    tf2x32(h0, h1, 1u, 4u, b0, b1);
    tf2x32(h0, h1, 2u, 5u, c0, c1);
    K[h][0] = a0; K[h][1] = b0;   // ke
    K[h][2] = c0; K[h][3] = a1;   // km
    K[h][4] = b1; K[h][5] = c1;   // kp
#endif
  }

  const int nbE = (NNZ + 255) / 256;
  const int nb1 = (NTOT + 1023) / 1024;  // 293
  hipMemsetAsync(cnt, 0, sizeof(int) * NTOT, stream);
  k_hist<<<nbE, 256, 0, stream>>>(rows, cnt, NNZ);
  k_scan1<<<nb1, 256, 0, stream>>>(cnt, rowst, bsum, NTOT);
  k_scan2<<<1, 512, 0, stream>>>(bsum, nb1);
  k_scan3<<<(NTOT + 255) / 256, 256, 0, stream>>>(rowst, bsum, fill, NTOT);
  k_scatter<<<nbE, 256, 0, stream>>>(rows, cols, fill, cols_s, idx_s, NNZ);
  k_rowsort<<<(NTOT + 255) / 256, 256, 0, stream>>>(rowst, cnt, cols_s, idx_s, NTOT);
  k_init<<<(NTOT * DIM / 4 + 255) / 256, 256, 0, stream>>>(ue, ie, aggA, out);

  float* X = aggA;
  float* Y = aggB;
  for (int h = 0; h < 3; h++) {
    k_edgeval<<<nbE, 256, 0, stream>>>(adjv, idx_s, vals_h, K[h][0], K[h][1], NNZ);
    k_spmm<<<(NTOT * DIM + 255) / 256, 256, 0, stream>>>(rowst, cnt, cols_s, vals_h, X, Y);
    k_post<<<(NTOT * DIM + 255) / 256, 256, 0, stream>>>(Y, gamma, beta, out,
                                                         K[h][2], K[h][3], K[h][4], K[h][5], h);
    float* tmp = X; X = Y; Y = tmp;
  }
}

// Round 2
// 1203.638 us; speedup vs baseline: 1.3767x; 1.3767x over previous
//
#include <hip/hip_runtime.h>
#include <stdint.h>

// ---------------- problem constants ----------------
#define N_USERS 100000
#define N_ITEMS 200000
#define NTOT    300000
#define DIM     64
#define NNZ     4000000

// output layout (floats)
#define OUT_I    25600000   // after users embs  (100000*4*64)
#define OUT_CLU  76800000   // after items embs  (+200000*4*64)
#define OUT_CLI  83200000   // after users cl    (+100000*64)

#define COLMASK  0x7FFFFu   // 19 bits (NTOT < 524288)

// ---------------- threefry2x32 (20 rounds) ----------------
__host__ __device__ __forceinline__ void tf2x32(uint32_t k0, uint32_t k1,
                                                uint32_t x0, uint32_t x1,
                                                uint32_t& o0, uint32_t& o1) {
  uint32_t ks2 = k0 ^ k1 ^ 0x1BD11BDAu;
#define TFR(r) { x0 += x1; x1 = (x1 << (r)) | (x1 >> (32 - (r))); x1 ^= x0; }
  x0 += k0; x1 += k1;
  TFR(13) TFR(15) TFR(26) TFR(6)
  x0 += k1;  x1 += ks2 + 1u;
  TFR(17) TFR(29) TFR(16) TFR(24)
  x0 += ks2; x1 += k0 + 2u;
  TFR(13) TFR(15) TFR(26) TFR(6)
  x0 += k0;  x1 += k1 + 3u;
  TFR(17) TFR(29) TFR(16) TFR(24)
  x0 += k1;  x1 += ks2 + 4u;
  TFR(13) TFR(15) TFR(26) TFR(6)
  x0 += ks2; x1 += k0 + 5u;
#undef TFR
  o0 = x0; o1 = x1;
}

// partitionable threefry: per-element bits = fold of counter j
__device__ __forceinline__ uint32_t rnd_bits(uint32_t k0, uint32_t k1, uint32_t j) {
  uint32_t a, b;
  tf2x32(k0, k1, 0u, j, a, b);
  return a ^ b;
}

__device__ __forceinline__ float u01f(uint32_t bits) {
  return __uint_as_float((bits >> 9) | 0x3f800000u) - 1.0f;
}

// ---------------- CSR build ----------------
__global__ void k_hist(const int* __restrict__ rows, int* __restrict__ cnt, int nnz) {
  int e = blockIdx.x * blockDim.x + threadIdx.x;
  if (e < nnz) atomicAdd(&cnt[rows[e]], 1);
}

__global__ void k_scan1(const int* __restrict__ cnt, int* __restrict__ rowstart,
                        int* __restrict__ bsum, int n) {
  __shared__ int sm[256];
  int t = threadIdx.x;
  int base = blockIdx.x * 1024 + t * 4;
  int v0 = (base     < n) ? cnt[base]     : 0;
  int v1 = (base + 1 < n) ? cnt[base + 1] : 0;
  int v2 = (base + 2 < n) ? cnt[base + 2] : 0;
  int v3 = (base + 3 < n) ? cnt[base + 3] : 0;
  int s = v0 + v1 + v2 + v3;
  sm[t] = s;
  __syncthreads();
  for (int off = 1; off < 256; off <<= 1) {
    int y = (t >= off) ? sm[t - off] : 0;
    __syncthreads();
    sm[t] += y;
    __syncthreads();
  }
  int ex = sm[t] - s;
  if (base     < n) rowstart[base]     = ex;
  if (base + 1 < n) rowstart[base + 1] = ex + v0;
  if (base + 2 < n) rowstart[base + 2] = ex + v0 + v1;
  if (base + 3 < n) rowstart[base + 3] = ex + v0 + v1 + v2;
  if (t == 255) bsum[blockIdx.x] = sm[255];
}

__global__ void k_scan2(int* bsum, int nb) {
  __shared__ int sm[512];
  int t = threadIdx.x;
  int v = (t < nb) ? bsum[t] : 0;
  sm[t] = v;
  __syncthreads();
  for (int off = 1; off < 512; off <<= 1) {
    int y = (t >= off) ? sm[t - off] : 0;
    __syncthreads();
    sm[t] += y;
    __syncthreads();
  }
  if (t < nb) bsum[t] = sm[t] - v;  // exclusive block offsets
}

__global__ void k_scan3(int* rowstart, const int* __restrict__ bsum, int* fill, int n) {
  int i = blockIdx.x * blockDim.x + threadIdx.x;
  if (i < n) {
    int s = rowstart[i] + bsum[i >> 10];
    rowstart[i] = s;
    fill[i] = s;
  }
}

// scatter edges to CSR order; pack col + 3 hop edge-masks + premultiplied value
// into a single uint2 (one cache line touch per edge).
__global__ void k_scatter_pack(const int* __restrict__ rows, const int* __restrict__ cols,
                               const float* __restrict__ adjv, int* fill,
                               uint2* __restrict__ packed,
                               uint32_t ke00, uint32_t ke01,
                               uint32_t ke10, uint32_t ke11,
                               uint32_t ke20, uint32_t ke21, int nnz) {
  int e = blockIdx.x * blockDim.x + threadIdx.x;
  if (e >= nnz) return;
  int r = rows[e];
  uint32_t c = (uint32_t)cols[e];
  // edge_mask_h = floor(0.5 + u) = (u >= 0.5) = top bit of threefry output
  uint32_t m0 = rnd_bits(ke00, ke01, (uint32_t)e) >> 31;
  uint32_t m1 = rnd_bits(ke10, ke11, (uint32_t)e) >> 31;
  uint32_t m2 = rnd_bits(ke20, ke21, (uint32_t)e) >> 31;
  uint32_t meta = c | (m0 << 19) | (m1 << 20) | (m2 << 21);
  float v2 = adjv[e] * 2.0f;  // 1/(1-0.5) premultiplied (exact)
  int pos = atomicAdd(&fill[r], 1);
  packed[pos] = make_uint2(meta, __float_as_uint(v2));
}

// ---------------- hop 0 init: agg = concat(ue, ie); out slot 0 ----------------
__global__ void k_init(const float* __restrict__ ue, const float* __restrict__ ie,
                       float* __restrict__ agg, float* __restrict__ out) {
  int t = blockIdx.x * blockDim.x + threadIdx.x;
  if (t >= NTOT * DIM / 4) return;
  int j = t * 4;
  int r = j >> 6;
  int d = j & 63;
  float4 v = (r < N_USERS) ? *reinterpret_cast<const float4*>(ue + j)
                           : *reinterpret_cast<const float4*>(ie + (j - N_USERS * DIM));
  *reinterpret_cast<float4*>(agg + j) = v;
  int o = (r < N_USERS) ? (r * 256 + d) : (OUT_I + (r - N_USERS) * 256 + d);
  *reinterpret_cast<float4*>(out + o) = v;
}

// ---------------- fused hop: SpMM + LN + dropout + perturb + outputs ----------------
// one 64-lane wave per output row, lane = dim
__global__ __launch_bounds__(256) void k_hop(const int* __restrict__ rowstart,
                                             const int* __restrict__ cnt,
                                             const uint2* __restrict__ packed,
                                             const float* __restrict__ X,
                                             float* __restrict__ Xn,
                                             const float* __restrict__ gamma,
                                             const float* __restrict__ beta,
                                             float* __restrict__ out,
                                             uint32_t km0, uint32_t km1,
                                             uint32_t kp0, uint32_t kp1, int hop) {
  int gid = blockIdx.x * blockDim.x + threadIdx.x;
  int r = gid >> 6;
  int lane = gid & 63;
  if (r >= NTOT) return;
  int s = rowstart[r], m = cnt[r];
  const uint32_t hb = 0x80000u << hop;  // hop mask bit

  float acc = 0.0f;
  int k = 0;
  for (; k + 3 < m; k += 4) {
    uint2 p0 = packed[s + k];
    uint2 p1 = packed[s + k + 1];
    uint2 p2 = packed[s + k + 2];
    uint2 p3 = packed[s + k + 3];
    if (p0.x & hb) acc = fmaf(__uint_as_float(p0.y), X[(p0.x & COLMASK) * DIM + lane], acc);
    if (p1.x & hb) acc = fmaf(__uint_as_float(p1.y), X[(p1.x & COLMASK) * DIM + lane], acc);
    if (p2.x & hb) acc = fmaf(__uint_as_float(p2.y), X[(p2.x & COLMASK) * DIM + lane], acc);
    if (p3.x & hb) acc = fmaf(__uint_as_float(p3.y), X[(p3.x & COLMASK) * DIM + lane], acc);
  }
  for (; k < m; k++) {
    uint2 p = packed[s + k];
    if (p.x & hb) acc = fmaf(__uint_as_float(p.y), X[(p.x & COLMASK) * DIM + lane], acc);
  }

  float x = acc;

  // layer norm over the 64 lanes of this wave
  float t = x;
#pragma unroll
  for (int mm = 32; mm >= 1; mm >>= 1) t += __shfl_xor(t, mm, 64);
  float mu = t * (1.0f / 64.0f);
  float dv = x - mu;
  float t2 = dv * dv;
#pragma unroll
  for (int mm = 32; mm >= 1; mm >>= 1) t2 += __shfl_xor(t2, mm, 64);
  float var = t2 * (1.0f / 64.0f);
  x = dv * rsqrtf(var + 1e-5f) * gamma[lane] + beta[lane];

  // message dropout: keep iff uniform >= 0.1
  uint32_t j = (uint32_t)(r * DIM + lane);
  float um = u01f(rnd_bits(km0, km1, j));
  const float INV_KEEP = (float)(1.0 / 0.9);
  x = x * ((um >= 0.1f) ? INV_KEEP : 0.0f);

  // perturbation: normal via erfinv of uniform(lo, 1), row-normalized
  float un = u01f(rnd_bits(kp0, kp1, j));
  const float LO = __uint_as_float(0xBF7FFFFFu);  // nextafter(-1, 0)
  float val = un * 2.0f + LO;
  float nz = 0x1.6a09e6p+0f * erfinvf(val);        // sqrt(2) * erfinv
  float s2 = nz * nz;
#pragma unroll
  for (int mm = 32; mm >= 1; mm >>= 1) s2 += __shfl_xor(s2, mm, 64);
  float nrm = sqrtf(s2);
  float nh = nz / (nrm + 1e-12f);
  float sg = (x > 0.0f) ? 1.0f : ((x < 0.0f) ? -1.0f : 0.0f);
  x = x + sg * nh * 0.03f;

  // write next-hop agg + outputs
  Xn[r * DIM + lane] = x;
  int h1 = hop + 1;
  if (r < N_USERS) {
    out[r * 256 + h1 * 64 + lane] = x;
    if (hop == 0) out[OUT_CLU + r * 64 + lane] = x;
  } else {
    int i = r - N_USERS;
    out[OUT_I + i * 256 + h1 * 64 + lane] = x;
    if (hop == 0) out[OUT_CLI + i * 64 + lane] = x;
  }
}

// ---------------- launch ----------------
extern "C" void kernel_launch(void* const* d_in, const int* in_sizes, int n_in,
                              void* d_out, int out_size, void* d_ws, size_t ws_size,
                              hipStream_t stream) {
  (void)in_sizes; (void)n_in; (void)out_size; (void)ws_size;
  const float* ue    = (const float*)d_in[0];
  const float* ie    = (const float*)d_in[1];
  const float* adjv  = (const float*)d_in[2];
  const float* gamma = (const float*)d_in[3];
  const float* beta  = (const float*)d_in[4];
  const int*   adji  = (const int*)d_in[5];
  const int* rows = adji;
  const int* cols = adji + NNZ;
  float* out = (float*)d_out;

  char* ws = (char*)d_ws;
  size_t off = 0;
  auto alloc = [&](size_t bytes) -> void* {
    void* p = ws + off;
    off += (bytes + 255) & ~(size_t)255;
    return p;
  };
  float* aggA   = (float*)alloc(sizeof(float) * NTOT * DIM);
  float* aggB   = (float*)alloc(sizeof(float) * NTOT * DIM);
  int*   cnt    = (int*)alloc(sizeof(int) * NTOT);
  int*   rowst  = (int*)alloc(sizeof(int) * NTOT);
  int*   fill   = (int*)alloc(sizeof(int) * NTOT);
  int*   bsum   = (int*)alloc(sizeof(int) * 512);
  uint2* packed = (uint2*)alloc(sizeof(uint2) * NNZ);

  // host-side key derivation: kh = fold_in(key(42), hop); (ke,km,kp) = split(kh, 3)
  uint32_t K[3][6];
  for (uint32_t h = 0; h < 3; h++) {
    uint32_t h0, h1;
    tf2x32(0u, 42u, 0u, h, h0, h1);
    tf2x32(h0, h1, 0u, 0u, K[h][0], K[h][1]);  // ke
    tf2x32(h0, h1, 0u, 1u, K[h][2], K[h][3]);  // km
    tf2x32(h0, h1, 0u, 2u, K[h][4], K[h][5]);  // kp
  }

  const int nbE = (NNZ + 255) / 256;
  const int nb1 = (NTOT + 1023) / 1024;  // 293
  hipMemsetAsync(cnt, 0, sizeof(int) * NTOT, stream);
  k_hist<<<nbE, 256, 0, stream>>>(rows, cnt, NNZ);
  k_scan1<<<nb1, 256, 0, stream>>>(cnt, rowst, bsum, NTOT);
  k_scan2<<<1, 512, 0, stream>>>(bsum, nb1);
  k_scan3<<<(NTOT + 255) / 256, 256, 0, stream>>>(rowst, bsum, fill, NTOT);
  k_scatter_pack<<<nbE, 256, 0, stream>>>(rows, cols, adjv, fill, packed,
                                          K[0][0], K[0][1], K[1][0], K[1][1],
                                          K[2][0], K[2][1], NNZ);
  k_init<<<(NTOT * DIM / 4 + 255) / 256, 256, 0, stream>>>(ue, ie, aggA, out);

  float* X = aggA;
  float* Y = aggB;
  for (int h = 0; h < 3; h++) {
    k_hop<<<(NTOT * DIM + 255) / 256, 256, 0, stream>>>(rowst, cnt, packed, X, Y,
                                                        gamma, beta, out,
                                                        K[h][2], K[h][3], K[h][4], K[h][5], h);
    float* tmp = X; X = Y; Y = tmp;
  }
}

// Round 3
// 1140.942 us; speedup vs baseline: 1.4523x; 1.0550x over previous
//
#include <hip/hip_runtime.h>
#include <stdint.h>

// ---------------- problem constants ----------------
#define N_USERS 100000
#define N_ITEMS 200000
#define NTOT    300000
#define DIM     64
#define NNZ     4000000

// output layout (floats)
#define OUT_I    25600000   // after users embs  (100000*4*64)
#define OUT_CLU  76800000   // after items embs  (+200000*4*64)
#define OUT_CLI  83200000   // after users cl    (+100000*64)

#define COLMASK  0x7FFFFu   // 19 bits (NTOT < 524288)

// bucketed CSR build
#define RPB   1024                      // rows per bucket (rowlocal fits 10 bits)
#define NB    ((NTOT + RPB - 1) / RPB)  // 293 buckets
#define TILE  4096                      // edges per phase-1 workgroup

// ---------------- threefry2x32 (20 rounds) ----------------
__host__ __device__ __forceinline__ void tf2x32(uint32_t k0, uint32_t k1,
                                                uint32_t x0, uint32_t x1,
                                                uint32_t& o0, uint32_t& o1) {
  uint32_t ks2 = k0 ^ k1 ^ 0x1BD11BDAu;
#define TFR(r) { x0 += x1; x1 = (x1 << (r)) | (x1 >> (32 - (r))); x1 ^= x0; }
  x0 += k0; x1 += k1;
  TFR(13) TFR(15) TFR(26) TFR(6)
  x0 += k1;  x1 += ks2 + 1u;
  TFR(17) TFR(29) TFR(16) TFR(24)
  x0 += ks2; x1 += k0 + 2u;
  TFR(13) TFR(15) TFR(26) TFR(6)
  x0 += k0;  x1 += k1 + 3u;
  TFR(17) TFR(29) TFR(16) TFR(24)
  x0 += k1;  x1 += ks2 + 4u;
  TFR(13) TFR(15) TFR(26) TFR(6)
  x0 += ks2; x1 += k0 + 5u;
#undef TFR
  o0 = x0; o1 = x1;
}

// partitionable threefry: per-element bits = fold of counter j
__device__ __forceinline__ uint32_t rnd_bits(uint32_t k0, uint32_t k1, uint32_t j) {
  uint32_t a, b;
  tf2x32(k0, k1, 0u, j, a, b);
  return a ^ b;
}

__device__ __forceinline__ float u01f(uint32_t bits) {
  return __uint_as_float((bits >> 9) | 0x3f800000u) - 1.0f;
}

// ---------------- CSR row histogram + scan ----------------
__global__ void k_hist(const int* __restrict__ rows, int* __restrict__ cnt, int nnz) {
  int e = blockIdx.x * blockDim.x + threadIdx.x;
  if (e < nnz) atomicAdd(&cnt[rows[e]], 1);
}

__global__ void k_scan1(const int* __restrict__ cnt, int* __restrict__ rowstart,
                        int* __restrict__ bsum, int n) {
  __shared__ int sm[256];
  int t = threadIdx.x;
  int base = blockIdx.x * 1024 + t * 4;
  int v0 = (base     < n) ? cnt[base]     : 0;
  int v1 = (base + 1 < n) ? cnt[base + 1] : 0;
  int v2 = (base + 2 < n) ? cnt[base + 2] : 0;
  int v3 = (base + 3 < n) ? cnt[base + 3] : 0;
  int s = v0 + v1 + v2 + v3;
  sm[t] = s;
  __syncthreads();
  for (int off = 1; off < 256; off <<= 1) {
    int y = (t >= off) ? sm[t - off] : 0;
    __syncthreads();
    sm[t] += y;
    __syncthreads();
  }
  int ex = sm[t] - s;
  if (base     < n) rowstart[base]     = ex;
  if (base + 1 < n) rowstart[base + 1] = ex + v0;
  if (base + 2 < n) rowstart[base + 2] = ex + v0 + v1;
  if (base + 3 < n) rowstart[base + 3] = ex + v0 + v1 + v2;
  if (t == 255) bsum[blockIdx.x] = sm[255];
}

__global__ void k_scan2(int* bsum, int nb) {
  __shared__ int sm[512];
  int t = threadIdx.x;
  int v = (t < nb) ? bsum[t] : 0;
  sm[t] = v;
  __syncthreads();
  for (int off = 1; off < 512; off <<= 1) {
    int y = (t >= off) ? sm[t - off] : 0;
    __syncthreads();
    sm[t] += y;
    __syncthreads();
  }
  if (t < nb) bsum[t] = sm[t] - v;  // exclusive block offsets
}

__global__ void k_scan3(int* rowstart, const int* __restrict__ bsum, int n) {
  int i = blockIdx.x * blockDim.x + threadIdx.x;
  if (i < n) rowstart[i] += bsum[i >> 10];
}

// per-bucket frontier init: gfill[b] = rowstart[first row of bucket]
__global__ void k_binit(const int* __restrict__ rowstart, int* __restrict__ gfill) {
  int b = blockIdx.x * blockDim.x + threadIdx.x;
  if (b < NB) gfill[b] = rowstart[b << 10];
}

// ---------------- phase 1: bin edges into bucket runs (locality-friendly) ----
// record: w0 = col | m0<<19 | m1<<20 | m2<<21 | rowlocal<<22 ; w1 = val*2
__global__ __launch_bounds__(256) void k_bin(const int* __restrict__ rows,
                                             const int* __restrict__ cols,
                                             const float* __restrict__ adjv,
                                             int* __restrict__ gfill,
                                             uint2* __restrict__ staging,
                                             uint32_t ke00, uint32_t ke01,
                                             uint32_t ke10, uint32_t ke11,
                                             uint32_t ke20, uint32_t ke21, int nnz) {
  __shared__ int hist[NB];
  __shared__ int gb[NB];
  int t = threadIdx.x;
  for (int i = t; i < NB; i += 256) hist[i] = 0;
  __syncthreads();
  int base = blockIdx.x * TILE;

  uint32_t recx[16];
  float    recy[16];
  uint32_t bl[16];   // (bucket<<13) | localpos, 0xFFFFFFFF = invalid

#pragma unroll
  for (int i = 0; i < 16; i++) {
    int e = base + i * 256 + t;
    bl[i] = 0xFFFFFFFFu;
    if (e < nnz) {
      int r = rows[e];
      uint32_t c = (uint32_t)cols[e];
      uint32_t m0 = rnd_bits(ke00, ke01, (uint32_t)e) >> 31;
      uint32_t m1 = rnd_bits(ke10, ke11, (uint32_t)e) >> 31;
      uint32_t m2 = rnd_bits(ke20, ke21, (uint32_t)e) >> 31;
      recx[i] = c | (m0 << 19) | (m1 << 20) | (m2 << 21) | ((uint32_t)(r & (RPB - 1)) << 22);
      recy[i] = adjv[e] * 2.0f;
      int b = r >> 10;
      int lp = atomicAdd(&hist[b], 1);
      bl[i] = ((uint32_t)b << 13) | (uint32_t)lp;
    }
  }
  __syncthreads();
  for (int i = t; i < NB; i += 256) {
    int c = hist[i];
    gb[i] = c ? atomicAdd(&gfill[i], c) : 0;
  }
  __syncthreads();
#pragma unroll
  for (int i = 0; i < 16; i++) {
    if (bl[i] != 0xFFFFFFFFu) {
      int b  = (int)(bl[i] >> 13);
      int lp = (int)(bl[i] & 0x1FFFu);
      staging[gb[b] + lp] = make_uint2(recx[i], __float_as_uint(recy[i]));
    }
  }
}

// ---------------- phase 2: place bucket records at exact CSR positions -------
__global__ __launch_bounds__(256) void k_place(const int* __restrict__ rowstart,
                                               const int* __restrict__ gfill,
                                               const uint2* __restrict__ staging,
                                               uint2* __restrict__ packed) {
  __shared__ int rowfill[RPB];
  int b = blockIdx.x;
  int r0 = b << 10;
  int nr = min(RPB, NTOT - r0);
  for (int j = threadIdx.x; j < nr; j += 256) rowfill[j] = rowstart[r0 + j];
  __syncthreads();
  int s0 = rowstart[r0];
  int s1 = gfill[b];
  for (int i = s0 + (int)threadIdx.x; i < s1; i += 256) {
    uint2 rec = staging[i];
    int rl = (int)(rec.x >> 22);
    int pos = atomicAdd(&rowfill[rl], 1);
    packed[pos] = make_uint2(rec.x & 0x3FFFFFu, rec.y);
  }
}

// ---------------- hop-0 output slot only (agg copy skipped) ----------------
__global__ void k_init0(const float* __restrict__ ue, const float* __restrict__ ie,
                        float* __restrict__ out) {
  int t = blockIdx.x * blockDim.x + threadIdx.x;
  if (t >= NTOT * DIM / 4) return;
  int j = t * 4;
  int r = j >> 6;
  int d = j & 63;
  float4 v = (r < N_USERS) ? *reinterpret_cast<const float4*>(ue + j)
                           : *reinterpret_cast<const float4*>(ie + (j - N_USERS * DIM));
  int o = (r < N_USERS) ? (r * 256 + d) : (OUT_I + (r - N_USERS) * 256 + d);
  *reinterpret_cast<float4*>(out + o) = v;
}

// ---------------- fused hop: SpMM + LN + dropout + perturb + outputs ----------------
// one 64-lane wave per output row, lane = dim. Gather source is split:
// col < split -> Xa[col], else Xb[col - split]  (hop 0 reads ue/ie directly)
__global__ __launch_bounds__(256) void k_hop(const int* __restrict__ rowstart,
                                             const int* __restrict__ cnt,
                                             const uint2* __restrict__ packed,
                                             const float* __restrict__ Xa,
                                             const float* __restrict__ Xb,
                                             int split,
                                             float* __restrict__ Xn,
                                             const float* __restrict__ gamma,
                                             const float* __restrict__ beta,
                                             float* __restrict__ out,
                                             uint32_t km0, uint32_t km1,
                                             uint32_t kp0, uint32_t kp1, int hop) {
  int gid = blockIdx.x * blockDim.x + threadIdx.x;
  int r = gid >> 6;
  int lane = gid & 63;
  if (r >= NTOT) return;
  int s = rowstart[r], m = cnt[r];
  const uint32_t hb = 0x80000u << hop;  // hop mask bit

  float acc = 0.0f;
  int k = 0;
  for (; k + 7 < m; k += 8) {
    uint2 p0 = packed[s + k];
    uint2 p1 = packed[s + k + 1];
    uint2 p2 = packed[s + k + 2];
    uint2 p3 = packed[s + k + 3];
    uint2 p4 = packed[s + k + 4];
    uint2 p5 = packed[s + k + 5];
    uint2 p6 = packed[s + k + 6];
    uint2 p7 = packed[s + k + 7];
#define GATH(p)                                                                  \
    if (p.x & hb) {                                                              \
      int c = (int)(p.x & COLMASK);                                              \
      const float* xp = (c < split) ? (Xa + c * DIM) : (Xb + (c - split) * DIM); \
      acc = fmaf(__uint_as_float(p.y), xp[lane], acc);                           \
    }
    GATH(p0) GATH(p1) GATH(p2) GATH(p3) GATH(p4) GATH(p5) GATH(p6) GATH(p7)
  }
  for (; k < m; k++) {
    uint2 p = packed[s + k];
    GATH(p)
  }
#undef GATH

  float x = acc;

  // layer norm over the 64 lanes of this wave
  float t = x;
#pragma unroll
  for (int mm = 32; mm >= 1; mm >>= 1) t += __shfl_xor(t, mm, 64);
  float mu = t * (1.0f / 64.0f);
  float dv = x - mu;
  float t2 = dv * dv;
#pragma unroll
  for (int mm = 32; mm >= 1; mm >>= 1) t2 += __shfl_xor(t2, mm, 64);
  float var = t2 * (1.0f / 64.0f);
  x = dv * rsqrtf(var + 1e-5f) * gamma[lane] + beta[lane];

  // message dropout: keep iff uniform >= 0.1
  uint32_t j = (uint32_t)(r * DIM + lane);
  float um = u01f(rnd_bits(km0, km1, j));
  const float INV_KEEP = (float)(1.0 / 0.9);
  x = x * ((um >= 0.1f) ? INV_KEEP : 0.0f);

  // perturbation: normal via erfinv of uniform(lo, 1), row-normalized
  float un = u01f(rnd_bits(kp0, kp1, j));
  const float LO = __uint_as_float(0xBF7FFFFFu);  // nextafter(-1, 0)
  float val = un * 2.0f + LO;
  float nz = 0x1.6a09e6p+0f * erfinvf(val);        // sqrt(2) * erfinv
  float s2 = nz * nz;
#pragma unroll
  for (int mm = 32; mm >= 1; mm >>= 1) s2 += __shfl_xor(s2, mm, 64);
  float nrm = sqrtf(s2);
  float nh = nz / (nrm + 1e-12f);
  float sg = (x > 0.0f) ? 1.0f : ((x < 0.0f) ? -1.0f : 0.0f);
  x = x + sg * nh * 0.03f;

  // write next-hop agg + outputs
  Xn[r * DIM + lane] = x;
  int h1 = hop + 1;
  if (r < N_USERS) {
    out[r * 256 + h1 * 64 + lane] = x;
    if (hop == 0) out[OUT_CLU + r * 64 + lane] = x;
  } else {
    int i = r - N_USERS;
    out[OUT_I + i * 256 + h1 * 64 + lane] = x;
    if (hop == 0) out[OUT_CLI + i * 64 + lane] = x;
  }
}

// ---------------- launch ----------------
extern "C" void kernel_launch(void* const* d_in, const int* in_sizes, int n_in,
                              void* d_out, int out_size, void* d_ws, size_t ws_size,
                              hipStream_t stream) {
  (void)in_sizes; (void)n_in; (void)out_size; (void)ws_size;
  const float* ue    = (const float*)d_in[0];
  const float* ie    = (const float*)d_in[1];
  const float* adjv  = (const float*)d_in[2];
  const float* gamma = (const float*)d_in[3];
  const float* beta  = (const float*)d_in[4];
  const int*   adji  = (const int*)d_in[5];
  const int* rows = adji;
  const int* cols = adji + NNZ;
  float* out = (float*)d_out;

  char* ws = (char*)d_ws;
  size_t off = 0;
  auto alloc = [&](size_t bytes) -> void* {
    void* p = ws + off;
    off += (bytes + 255) & ~(size_t)255;
    return p;
  };
  float* aggA   = (float*)alloc(sizeof(float) * NTOT * DIM);
  float* aggB   = (float*)alloc(sizeof(float) * NTOT * DIM);
  int*   cnt    = (int*)alloc(sizeof(int) * NTOT);
  int*   rowst  = (int*)alloc(sizeof(int) * NTOT);
  int*   gfill  = (int*)alloc(sizeof(int) * NB);
  int*   bsum   = (int*)alloc(sizeof(int) * 512);
  uint2* packed = (uint2*)alloc(sizeof(uint2) * NNZ);
  uint2* staging = (uint2*)aggB;  // alias: aggB first written at hop 1, staging dead by then

  // host-side key derivation: kh = fold_in(key(42), hop); (ke,km,kp) = split(kh, 3)
  uint32_t K[3][6];
  for (uint32_t h = 0; h < 3; h++) {
    uint32_t h0, h1;
    tf2x32(0u, 42u, 0u, h, h0, h1);
    tf2x32(h0, h1, 0u, 0u, K[h][0], K[h][1]);  // ke
    tf2x32(h0, h1, 0u, 1u, K[h][2], K[h][3]);  // km
    tf2x32(h0, h1, 0u, 2u, K[h][4], K[h][5]);  // kp
  }

  const int nbE = (NNZ + 255) / 256;
  const int nb1 = (NTOT + 1023) / 1024;  // 293
  hipMemsetAsync(cnt, 0, sizeof(int) * NTOT, stream);
  k_hist<<<nbE, 256, 0, stream>>>(rows, cnt, NNZ);
  k_scan1<<<nb1, 256, 0, stream>>>(cnt, rowst, bsum, NTOT);
  k_scan2<<<1, 512, 0, stream>>>(bsum, nb1);
  k_scan3<<<(NTOT + 255) / 256, 256, 0, stream>>>(rowst, bsum, NTOT);
  k_binit<<<(NB + 255) / 256, 256, 0, stream>>>(rowst, gfill);
  k_bin<<<(NNZ + TILE - 1) / TILE, 256, 0, stream>>>(rows, cols, adjv, gfill, staging,
                                                     K[0][0], K[0][1], K[1][0], K[1][1],
                                                     K[2][0], K[2][1], NNZ);
  k_place<<<NB, 256, 0, stream>>>(rowst, gfill, staging, packed);
  k_init0<<<(NTOT * DIM / 4 + 255) / 256, 256, 0, stream>>>(ue, ie, out);

  float* X = aggA;
  float* Y = aggB;
  for (int h = 0; h < 3; h++) {
    const float* Xa = (h == 0) ? ue : X;
    const float* Xb = (h == 0) ? ie : X;
    int split = (h == 0) ? N_USERS : NTOT;
    k_hop<<<(NTOT * DIM + 255) / 256, 256, 0, stream>>>(rowst, cnt, packed, Xa, Xb, split,
                                                        Y, gamma, beta, out,
                                                        K[h][2], K[h][3], K[h][4], K[h][5], h);
    if (h == 0) { X = aggB; Y = aggA; }       // hop0: ue/ie -> aggB? no: Y was aggB
    else { float* tmp = X; X = Y; Y = tmp; }
  }
}

// Round 5
// 1068.083 us; speedup vs baseline: 1.5514x; 1.0682x over previous
//
#include <hip/hip_runtime.h>
#include <stdint.h>

// ---------------- problem constants ----------------
#define N_USERS 100000
#define N_ITEMS 200000
#define NTOT    300000
#define DIM     64
#define NNZ     4000000

// output layout (floats)
#define OUT_I    25600000   // after users embs  (100000*4*64)
#define OUT_CLU  76800000   // after items embs  (+200000*4*64)
#define OUT_CLI  83200000   // after users cl    (+100000*64)

#define COLMASK  0x7FFFFu   // 19 bits (NTOT < 524288)

// bucketed CSR build
#define RPB   1024                      // rows per bucket (rowlocal fits 10 bits)
#define NB    ((NTOT + RPB - 1) / RPB)  // 293 buckets
#define TILE  4096                      // edges per phase-1 workgroup

typedef float floatx4 __attribute__((ext_vector_type(4)));  // NT-store-compatible

// ---------------- threefry2x32 (20 rounds) ----------------
__host__ __device__ __forceinline__ void tf2x32(uint32_t k0, uint32_t k1,
                                                uint32_t x0, uint32_t x1,
                                                uint32_t& o0, uint32_t& o1) {
  uint32_t ks2 = k0 ^ k1 ^ 0x1BD11BDAu;
#define TFR(r) { x0 += x1; x1 = (x1 << (r)) | (x1 >> (32 - (r))); x1 ^= x0; }
  x0 += k0; x1 += k1;
  TFR(13) TFR(15) TFR(26) TFR(6)
  x0 += k1;  x1 += ks2 + 1u;
  TFR(17) TFR(29) TFR(16) TFR(24)
  x0 += ks2; x1 += k0 + 2u;
  TFR(13) TFR(15) TFR(26) TFR(6)
  x0 += k0;  x1 += k1 + 3u;
  TFR(17) TFR(29) TFR(16) TFR(24)
  x0 += k1;  x1 += ks2 + 4u;
  TFR(13) TFR(15) TFR(26) TFR(6)
  x0 += ks2; x1 += k0 + 5u;
#undef TFR
  o0 = x0; o1 = x1;
}

// partitionable threefry: per-element bits = fold of counter j
__device__ __forceinline__ uint32_t rnd_bits(uint32_t k0, uint32_t k1, uint32_t j) {
  uint32_t a, b;
  tf2x32(k0, k1, 0u, j, a, b);
  return a ^ b;
}

__device__ __forceinline__ float u01f(uint32_t bits) {
  return __uint_as_float((bits >> 9) | 0x3f800000u) - 1.0f;
}

// ---------------- CSR row histogram + scan ----------------
__global__ void k_hist(const int* __restrict__ rows, int* __restrict__ cnt, int nnz) {
  int e = blockIdx.x * blockDim.x + threadIdx.x;
  if (e < nnz) atomicAdd(&cnt[rows[e]], 1);
}

__global__ void k_scan1(const int* __restrict__ cnt, int* __restrict__ rowstart,
                        int* __restrict__ bsum, int n) {
  __shared__ int sm[256];
  int t = threadIdx.x;
  int base = blockIdx.x * 1024 + t * 4;
  int v0 = (base     < n) ? cnt[base]     : 0;
  int v1 = (base + 1 < n) ? cnt[base + 1] : 0;
  int v2 = (base + 2 < n) ? cnt[base + 2] : 0;
  int v3 = (base + 3 < n) ? cnt[base + 3] : 0;
  int s = v0 + v1 + v2 + v3;
  sm[t] = s;
  __syncthreads();
  for (int off = 1; off < 256; off <<= 1) {
    int y = (t >= off) ? sm[t - off] : 0;
    __syncthreads();
    sm[t] += y;
    __syncthreads();
  }
  int ex = sm[t] - s;
  if (base     < n) rowstart[base]     = ex;
  if (base + 1 < n) rowstart[base + 1] = ex + v0;
  if (base + 2 < n) rowstart[base + 2] = ex + v0 + v1;
  if (base + 3 < n) rowstart[base + 3] = ex + v0 + v1 + v2;
  if (t == 255) bsum[blockIdx.x] = sm[255];
}

__global__ void k_scan2(int* bsum, int nb) {
  __shared__ int sm[512];
  int t = threadIdx.x;
  int v = (t < nb) ? bsum[t] : 0;
  sm[t] = v;
  __syncthreads();
  for (int off = 1; off < 512; off <<= 1) {
    int y = (t >= off) ? sm[t - off] : 0;
    __syncthreads();
    sm[t] += y;
    __syncthreads();
  }
  if (t < nb) bsum[t] = sm[t] - v;  // exclusive block offsets
}

__global__ void k_scan3(int* rowstart, const int* __restrict__ bsum, int n) {
  int i = blockIdx.x * blockDim.x + threadIdx.x;
  if (i < n) rowstart[i] += bsum[i >> 10];
  if (i == n) rowstart[i] = NNZ;  // sentinel so rowstart[r+1] is valid for last row
}

// per-bucket frontier init: gfill[b] = rowstart[first row of bucket]
__global__ void k_binit(const int* __restrict__ rowstart, int* __restrict__ gfill) {
  int b = blockIdx.x * blockDim.x + threadIdx.x;
  if (b < NB) gfill[b] = rowstart[b << 10];
}

// ---------------- phase 1: bin edges into bucket runs (locality-friendly) ----
// record: w0 = col | m0<<19 | m1<<20 | m2<<21 | rowlocal<<22 ; w1 = val*2
__global__ __launch_bounds__(256) void k_bin(const int* __restrict__ rows,
                                             const int* __restrict__ cols,
                                             const float* __restrict__ adjv,
                                             int* __restrict__ gfill,
                                             uint2* __restrict__ staging,
                                             uint32_t ke00, uint32_t ke01,
                                             uint32_t ke10, uint32_t ke11,
                                             uint32_t ke20, uint32_t ke21, int nnz) {
  __shared__ int hist[NB];
  __shared__ int gb[NB];
  int t = threadIdx.x;
  for (int i = t; i < NB; i += 256) hist[i] = 0;
  __syncthreads();
  int base = blockIdx.x * TILE;

  uint32_t recx[16];
  float    recy[16];
  uint32_t bl[16];   // (bucket<<13) | localpos, 0xFFFFFFFF = invalid

#pragma unroll
  for (int i = 0; i < 16; i++) {
    int e = base + i * 256 + t;
    bl[i] = 0xFFFFFFFFu;
    if (e < nnz) {
      int r = rows[e];
      uint32_t c = (uint32_t)cols[e];
      uint32_t m0 = rnd_bits(ke00, ke01, (uint32_t)e) >> 31;
      uint32_t m1 = rnd_bits(ke10, ke11, (uint32_t)e) >> 31;
      uint32_t m2 = rnd_bits(ke20, ke21, (uint32_t)e) >> 31;
      recx[i] = c | (m0 << 19) | (m1 << 20) | (m2 << 21) | ((uint32_t)(r & (RPB - 1)) << 22);
      recy[i] = adjv[e] * 2.0f;
      int b = r >> 10;
      int lp = atomicAdd(&hist[b], 1);
      bl[i] = ((uint32_t)b << 13) | (uint32_t)lp;
    }
  }
  __syncthreads();
  for (int i = t; i < NB; i += 256) {
    int c = hist[i];
    gb[i] = c ? atomicAdd(&gfill[i], c) : 0;
  }
  __syncthreads();
#pragma unroll
  for (int i = 0; i < 16; i++) {
    if (bl[i] != 0xFFFFFFFFu) {
      int b  = (int)(bl[i] >> 13);
      int lp = (int)(bl[i] & 0x1FFFu);
      staging[gb[b] + lp] = make_uint2(recx[i], __float_as_uint(recy[i]));
    }
  }
}

// ---------------- phase 2: place bucket records at exact CSR positions -------
__global__ __launch_bounds__(256) void k_place(const int* __restrict__ rowstart,
                                               const int* __restrict__ gfill,
                                               const uint2* __restrict__ staging,
                                               uint2* __restrict__ packed) {
  __shared__ int rowfill[RPB];
  int b = blockIdx.x;
  int r0 = b << 10;
  int nr = min(RPB, NTOT - r0);
  for (int j = threadIdx.x; j < nr; j += 256) rowfill[j] = rowstart[r0 + j];
  __syncthreads();
  int s0 = rowstart[r0];
  int s1 = gfill[b];
  for (int i = s0 + (int)threadIdx.x; i < s1; i += 256) {
    uint2 rec = staging[i];
    int rl = (int)(rec.x >> 22);
    int pos = atomicAdd(&rowfill[rl], 1);
    packed[pos] = make_uint2(rec.x & 0x3FFFFFu, rec.y);
  }
}

// ---------------- hop-0 output slot only (agg copy skipped) ----------------
__global__ void k_init0(const float* __restrict__ ue, const float* __restrict__ ie,
                        float* __restrict__ out) {
  int t = blockIdx.x * blockDim.x + threadIdx.x;
  if (t >= NTOT * DIM / 4) return;
  int j = t * 4;
  int r = j >> 6;
  int d = j & 63;
  floatx4 v = (r < N_USERS) ? *reinterpret_cast<const floatx4*>(ue + j)
                            : *reinterpret_cast<const floatx4*>(ie + (j - N_USERS * DIM));
  int o = (r < N_USERS) ? (r * 256 + d) : (OUT_I + (r - N_USERS) * 256 + d);
  __builtin_nontemporal_store(v, reinterpret_cast<floatx4*>(out + o));
}

// ---------------- fused hop: SpMM + LN + dropout + perturb + outputs ----------------
// one 64-lane wave per output row, lane = dim.
// HOP is compile-time: hop 0 gathers from ue/ie split, hops 1/2 from X.
template <int HOP>
__global__ __launch_bounds__(256) void k_hop(const int* __restrict__ rowstart,
                                             const uint2* __restrict__ packed,
                                             const float* __restrict__ Xa,
                                             const float* __restrict__ Xb,
                                             float* __restrict__ Xn,
                                             const float* __restrict__ gamma,
                                             const float* __restrict__ beta,
                                             float* __restrict__ out,
                                             uint32_t km0, uint32_t km1,
                                             uint32_t kp0, uint32_t kp1) {
  int gid = blockIdx.x * blockDim.x + threadIdx.x;
  int r = gid >> 6;
  int lane = gid & 63;
  if (r >= NTOT) return;
  int2 se = *reinterpret_cast<const int2*>(rowstart + r);  // {start, next start}
  int s = se.x, m = se.y - se.x;
  constexpr uint32_t hb = 0x80000u << HOP;  // hop mask bit

  float acc0 = 0.0f, acc1 = 0.0f;
  int k = 0;
#define GATH(p, a)                                                              \
    if (p.x & hb) {                                                             \
      int c = (int)(p.x & COLMASK);                                             \
      const float* xp;                                                          \
      if (HOP == 0) xp = (c < N_USERS) ? (Xa + c * DIM)                         \
                                       : (Xb + (c - N_USERS) * DIM);            \
      else          xp = Xa + c * DIM;                                          \
      a = fmaf(__uint_as_float(p.y), xp[lane], a);                              \
    }
  for (; k + 7 < m; k += 8) {
    uint2 p0 = packed[s + k];
    uint2 p1 = packed[s + k + 1];
    uint2 p2 = packed[s + k + 2];
    uint2 p3 = packed[s + k + 3];
    uint2 p4 = packed[s + k + 4];
    uint2 p5 = packed[s + k + 5];
    uint2 p6 = packed[s + k + 6];
    uint2 p7 = packed[s + k + 7];
    GATH(p0, acc0) GATH(p1, acc1) GATH(p2, acc0) GATH(p3, acc1)
    GATH(p4, acc0) GATH(p5, acc1) GATH(p6, acc0) GATH(p7, acc1)
  }
  for (; k < m; k++) {
    uint2 p = packed[s + k];
    GATH(p, acc0)
  }
#undef GATH

  float x = acc0 + acc1;

  // layer norm over the 64 lanes of this wave
  float t = x;
#pragma unroll
  for (int mm = 32; mm >= 1; mm >>= 1) t += __shfl_xor(t, mm, 64);
  float mu = t * (1.0f / 64.0f);
  float dv = x - mu;
  float t2 = dv * dv;
#pragma unroll
  for (int mm = 32; mm >= 1; mm >>= 1) t2 += __shfl_xor(t2, mm, 64);
  float var = t2 * (1.0f / 64.0f);
  x = dv * rsqrtf(var + 1e-5f) * gamma[lane] + beta[lane];

  // message dropout: keep iff uniform >= 0.1
  uint32_t j = (uint32_t)(r * DIM + lane);
  float um = u01f(rnd_bits(km0, km1, j));
  const float INV_KEEP = (float)(1.0 / 0.9);
  x = x * ((um >= 0.1f) ? INV_KEEP : 0.0f);

  // perturbation: normal via erfinv of uniform(lo, 1), row-normalized
  float un = u01f(rnd_bits(kp0, kp1, j));
  const float LO = __uint_as_float(0xBF7FFFFFu);  // nextafter(-1, 0)
  float val = un * 2.0f + LO;
  float nz = 0x1.6a09e6p+0f * erfinvf(val);        // sqrt(2) * erfinv
  float s2 = nz * nz;
#pragma unroll
  for (int mm = 32; mm >= 1; mm >>= 1) s2 += __shfl_xor(s2, mm, 64);
  float nrm = sqrtf(s2);
  float nh = nz / (nrm + 1e-12f);
  float sg = (x > 0.0f) ? 1.0f : ((x < 0.0f) ? -1.0f : 0.0f);
  x = x + sg * nh * 0.03f;

  // write next-hop agg (cached: gathered next hop) + outputs (streamed, never re-read)
  Xn[r * DIM + lane] = x;
  constexpr int h1 = HOP + 1;
  if (r < N_USERS) {
    __builtin_nontemporal_store(x, &out[r * 256 + h1 * 64 + lane]);
    if (HOP == 0) __builtin_nontemporal_store(x, &out[OUT_CLU + r * 64 + lane]);
  } else {
    int i = r - N_USERS;
    __builtin_nontemporal_store(x, &out[OUT_I + i * 256 + h1 * 64 + lane]);
    if (HOP == 0) __builtin_nontemporal_store(x, &out[OUT_CLI + i * 64 + lane]);
  }
}

// ---------------- launch ----------------
extern "C" void kernel_launch(void* const* d_in, const int* in_sizes, int n_in,
                              void* d_out, int out_size, void* d_ws, size_t ws_size,
                              hipStream_t stream) {
  (void)in_sizes; (void)n_in; (void)out_size; (void)ws_size;
  const float* ue    = (const float*)d_in[0];
  const float* ie    = (const float*)d_in[1];
  const float* adjv  = (const float*)d_in[2];
  const float* gamma = (const float*)d_in[3];
  const float* beta  = (const float*)d_in[4];
  const int*   adji  = (const int*)d_in[5];
  const int* rows = adji;
  const int* cols = adji + NNZ;
  float* out = (float*)d_out;

  char* ws = (char*)d_ws;
  size_t off = 0;
  auto alloc = [&](size_t bytes) -> void* {
    void* p = ws + off;
    off += (bytes + 255) & ~(size_t)255;
    return p;
  };
  float* aggA   = (float*)alloc(sizeof(float) * NTOT * DIM);
  float* aggB   = (float*)alloc(sizeof(float) * NTOT * DIM);
  int*   cnt    = (int*)alloc(sizeof(int) * NTOT);
  int*   rowst  = (int*)alloc(sizeof(int) * (NTOT + 1));
  int*   gfill  = (int*)alloc(sizeof(int) * NB);
  int*   bsum   = (int*)alloc(sizeof(int) * 512);
  uint2* packed = (uint2*)alloc(sizeof(uint2) * NNZ);
  uint2* staging = (uint2*)aggB;  // alias: aggB first written by hop 0 output, staging dead by then

  // host-side key derivation: kh = fold_in(key(42), hop); (ke,km,kp) = split(kh, 3)
  uint32_t K[3][6];
  for (uint32_t h = 0; h < 3; h++) {
    uint32_t h0, h1;
    tf2x32(0u, 42u, 0u, h, h0, h1);
    tf2x32(h0, h1, 0u, 0u, K[h][0], K[h][1]);  // ke
    tf2x32(h0, h1, 0u, 1u, K[h][2], K[h][3]);  // km
    tf2x32(h0, h1, 0u, 2u, K[h][4], K[h][5]);  // kp
  }

  const int nbE = (NNZ + 255) / 256;
  const int nb1 = (NTOT + 1023) / 1024;  // 293
  (void)hipMemsetAsync(cnt, 0, sizeof(int) * NTOT, stream);
  k_hist<<<nbE, 256, 0, stream>>>(rows, cnt, NNZ);
  k_scan1<<<nb1, 256, 0, stream>>>(cnt, rowst, bsum, NTOT);
  k_scan2<<<1, 512, 0, stream>>>(bsum, nb1);
  k_scan3<<<(NTOT + 256) / 256, 256, 0, stream>>>(rowst, bsum, NTOT);
  k_binit<<<(NB + 255) / 256, 256, 0, stream>>>(rowst, gfill);
  k_bin<<<(NNZ + TILE - 1) / TILE, 256, 0, stream>>>(rows, cols, adjv, gfill, staging,
                                                     K[0][0], K[0][1], K[1][0], K[1][1],
                                                     K[2][0], K[2][1], NNZ);
  k_place<<<NB, 256, 0, stream>>>(rowst, gfill, staging, packed);
  k_init0<<<(NTOT * DIM / 4 + 255) / 256, 256, 0, stream>>>(ue, ie, out);

  const int nbH = (NTOT * DIM + 255) / 256;
  // hop 0: gather from ue/ie, write aggB
  k_hop<0><<<nbH, 256, 0, stream>>>(rowst, packed, ue, ie, aggB, gamma, beta, out,
                                    K[0][2], K[0][3], K[0][4], K[0][5]);
  // hop 1: gather from aggB, write aggA
  k_hop<1><<<nbH, 256, 0, stream>>>(rowst, packed, aggB, nullptr, aggA, gamma, beta, out,
                                    K[1][2], K[1][3], K[1][4], K[1][5]);
  // hop 2: gather from aggA, write aggB
  k_hop<2><<<nbH, 256, 0, stream>>>(rowst, packed, aggA, nullptr, aggB, gamma, beta, out,
                                    K[2][2], K[2][3], K[2][4], K[2][5]);
}

// Round 6
// 922.115 us; speedup vs baseline: 1.7970x; 1.1583x over previous
//
#include <hip/hip_runtime.h>
#include <stdint.h>

// ---------------- problem constants ----------------
#define N_USERS 100000
#define N_ITEMS 200000
#define NTOT    300000
#define DIM     64
#define NNZ     4000000

// output layout (floats)
#define OUT_I    25600000   // after users embs  (100000*4*64)
#define OUT_CLU  76800000   // after items embs  (+200000*4*64)
#define OUT_CLI  83200000   // after users cl    (+100000*64)

#define COLMASK  0x7FFFFu   // 19 bits (NTOT < 524288)

// bucketed CSR build
#define RPB   1024                      // rows per bucket (rowlocal fits 10 bits)
#define NB    ((NTOT + RPB - 1) / RPB)  // 293 buckets
#define TILE  4096                      // edges per phase-1 workgroup

typedef float floatx4 __attribute__((ext_vector_type(4)));  // NT-store-compatible

// ---------------- threefry2x32 (20 rounds) ----------------
__host__ __device__ __forceinline__ void tf2x32(uint32_t k0, uint32_t k1,
                                                uint32_t x0, uint32_t x1,
                                                uint32_t& o0, uint32_t& o1) {
  uint32_t ks2 = k0 ^ k1 ^ 0x1BD11BDAu;
#define TFR(r) { x0 += x1; x1 = (x1 << (r)) | (x1 >> (32 - (r))); x1 ^= x0; }
  x0 += k0; x1 += k1;
  TFR(13) TFR(15) TFR(26) TFR(6)
  x0 += k1;  x1 += ks2 + 1u;
  TFR(17) TFR(29) TFR(16) TFR(24)
  x0 += ks2; x1 += k0 + 2u;
  TFR(13) TFR(15) TFR(26) TFR(6)
  x0 += k0;  x1 += k1 + 3u;
  TFR(17) TFR(29) TFR(16) TFR(24)
  x0 += k1;  x1 += ks2 + 4u;
  TFR(13) TFR(15) TFR(26) TFR(6)
  x0 += ks2; x1 += k0 + 5u;
#undef TFR
  o0 = x0; o1 = x1;
}

// partitionable threefry: per-element bits = fold of counter j
__device__ __forceinline__ uint32_t rnd_bits(uint32_t k0, uint32_t k1, uint32_t j) {
  uint32_t a, b;
  tf2x32(k0, k1, 0u, j, a, b);
  return a ^ b;
}

__device__ __forceinline__ float u01f(uint32_t bits) {
  return __uint_as_float((bits >> 9) | 0x3f800000u) - 1.0f;
}

// branchless single-precision erfinv (Giles 2010; same scheme XLA uses for f32)
__device__ __forceinline__ float erfinv_giles(float x) {
  float w = -__logf((1.0f - x) * (1.0f + x));
  float wc = w - 2.5f;
  float p1 = 2.81022636e-08f;
  p1 = fmaf(p1, wc, 3.43273939e-07f);
  p1 = fmaf(p1, wc, -3.5233877e-06f);
  p1 = fmaf(p1, wc, -4.39150654e-06f);
  p1 = fmaf(p1, wc, 0.00021858087f);
  p1 = fmaf(p1, wc, -0.00125372503f);
  p1 = fmaf(p1, wc, -0.00417768164f);
  p1 = fmaf(p1, wc, 0.246640727f);
  p1 = fmaf(p1, wc, 1.50140941f);
  float wt = __builtin_sqrtf(w) - 3.0f;
  float p2 = -0.000200214257f;
  p2 = fmaf(p2, wt, 0.000100950558f);
  p2 = fmaf(p2, wt, 0.00134934322f);
  p2 = fmaf(p2, wt, -0.00367342844f);
  p2 = fmaf(p2, wt, 0.00573950773f);
  p2 = fmaf(p2, wt, -0.0076224613f);
  p2 = fmaf(p2, wt, 0.00943887047f);
  p2 = fmaf(p2, wt, 1.00167406f);
  p2 = fmaf(p2, wt, 2.83297682f);
  float p = (w < 5.0f) ? p1 : p2;
  return p * x;
}

// ---------------- CSR row histogram + scan ----------------
__global__ void k_hist(const int* __restrict__ rows, int* __restrict__ cnt, int nnz) {
  int e = blockIdx.x * blockDim.x + threadIdx.x;
  if (e < nnz) atomicAdd(&cnt[rows[e]], 1);
}

__global__ void k_scan1(const int* __restrict__ cnt, int* __restrict__ rowstart,
                        int* __restrict__ bsum, int n) {
  __shared__ int sm[256];
  int t = threadIdx.x;
  int base = blockIdx.x * 1024 + t * 4;
  int v0 = (base     < n) ? cnt[base]     : 0;
  int v1 = (base + 1 < n) ? cnt[base + 1] : 0;
  int v2 = (base + 2 < n) ? cnt[base + 2] : 0;
  int v3 = (base + 3 < n) ? cnt[base + 3] : 0;
  int s = v0 + v1 + v2 + v3;
  sm[t] = s;
  __syncthreads();
  for (int off = 1; off < 256; off <<= 1) {
    int y = (t >= off) ? sm[t - off] : 0;
    __syncthreads();
    sm[t] += y;
    __syncthreads();
  }
  int ex = sm[t] - s;
  if (base     < n) rowstart[base]     = ex;
  if (base + 1 < n) rowstart[base + 1] = ex + v0;
  if (base + 2 < n) rowstart[base + 2] = ex + v0 + v1;
  if (base + 3 < n) rowstart[base + 3] = ex + v0 + v1 + v2;
  if (t == 255) bsum[blockIdx.x] = sm[255];
}

__global__ void k_scan2(int* bsum, int nb) {
  __shared__ int sm[512];
  int t = threadIdx.x;
  int v = (t < nb) ? bsum[t] : 0;
  sm[t] = v;
  __syncthreads();
  for (int off = 1; off < 512; off <<= 1) {
    int y = (t >= off) ? sm[t - off] : 0;
    __syncthreads();
    sm[t] += y;
    __syncthreads();
  }
  if (t < nb) bsum[t] = sm[t] - v;  // exclusive block offsets
}

__global__ void k_scan3(int* rowstart, const int* __restrict__ bsum, int n) {
  int i = blockIdx.x * blockDim.x + threadIdx.x;
  if (i < n) rowstart[i] += bsum[i >> 10];
  if (i == n) rowstart[i] = NNZ;  // sentinel so rowstart[r+1] is valid for last row
}

// per-bucket frontier init: gfill[b] = rowstart[first row of bucket]
__global__ void k_binit(const int* __restrict__ rowstart, int* __restrict__ gfill) {
  int b = blockIdx.x * blockDim.x + threadIdx.x;
  if (b < NB) gfill[b] = rowstart[b << 10];
}

// ---------------- phase 1: bin edges into bucket runs (locality-friendly) ----
// record: w0 = col | m0<<19 | m1<<20 | m2<<21 | rowlocal<<22 ; w1 = val*2
__global__ __launch_bounds__(256) void k_bin(const int* __restrict__ rows,
                                             const int* __restrict__ cols,
                                             const float* __restrict__ adjv,
                                             int* __restrict__ gfill,
                                             uint2* __restrict__ staging,
                                             uint32_t ke00, uint32_t ke01,
                                             uint32_t ke10, uint32_t ke11,
                                             uint32_t ke20, uint32_t ke21, int nnz) {
  __shared__ int hist[NB];
  __shared__ int gb[NB];
  int t = threadIdx.x;
  for (int i = t; i < NB; i += 256) hist[i] = 0;
  __syncthreads();
  int base = blockIdx.x * TILE;

  uint32_t recx[16];
  float    recy[16];
  uint32_t bl[16];   // (bucket<<13) | localpos, 0xFFFFFFFF = invalid

#pragma unroll
  for (int i = 0; i < 16; i++) {
    int e = base + i * 256 + t;
    bl[i] = 0xFFFFFFFFu;
    if (e < nnz) {
      int r = rows[e];
      uint32_t c = (uint32_t)cols[e];
      uint32_t m0 = rnd_bits(ke00, ke01, (uint32_t)e) >> 31;
      uint32_t m1 = rnd_bits(ke10, ke11, (uint32_t)e) >> 31;
      uint32_t m2 = rnd_bits(ke20, ke21, (uint32_t)e) >> 31;
      recx[i] = c | (m0 << 19) | (m1 << 20) | (m2 << 21) | ((uint32_t)(r & (RPB - 1)) << 22);
      recy[i] = adjv[e] * 2.0f;
      int b = r >> 10;
      int lp = atomicAdd(&hist[b], 1);
      bl[i] = ((uint32_t)b << 13) | (uint32_t)lp;
    }
  }
  __syncthreads();
  for (int i = t; i < NB; i += 256) {
    int c = hist[i];
    gb[i] = c ? atomicAdd(&gfill[i], c) : 0;
  }
  __syncthreads();
#pragma unroll
  for (int i = 0; i < 16; i++) {
    if (bl[i] != 0xFFFFFFFFu) {
      int b  = (int)(bl[i] >> 13);
      int lp = (int)(bl[i] & 0x1FFFu);
      staging[gb[b] + lp] = make_uint2(recx[i], __float_as_uint(recy[i]));
    }
  }
}

// ---------------- phase 2: place bucket records at exact CSR positions -------
__global__ __launch_bounds__(256) void k_place(const int* __restrict__ rowstart,
                                               const int* __restrict__ gfill,
                                               const uint2* __restrict__ staging,
                                               uint2* __restrict__ packed) {
  __shared__ int rowfill[RPB];
  int b = blockIdx.x;
  int r0 = b << 10;
  int nr = min(RPB, NTOT - r0);
  for (int j = threadIdx.x; j < nr; j += 256) rowfill[j] = rowstart[r0 + j];
  __syncthreads();
  int s0 = rowstart[r0];
  int s1 = gfill[b];
  for (int i = s0 + (int)threadIdx.x; i < s1; i += 256) {
    uint2 rec = staging[i];
    int rl = (int)(rec.x >> 22);
    int pos = atomicAdd(&rowfill[rl], 1);
    packed[pos] = make_uint2(rec.x & 0x3FFFFFu, rec.y);
  }
}

// ---------------- hop-0 output slot only (agg copy skipped) ----------------
__global__ void k_init0(const float* __restrict__ ue, const float* __restrict__ ie,
                        float* __restrict__ out) {
  int t = blockIdx.x * blockDim.x + threadIdx.x;
  if (t >= NTOT * DIM / 4) return;
  int j = t * 4;
  int r = j >> 6;
  int d = j & 63;
  floatx4 v = (r < N_USERS) ? *reinterpret_cast<const floatx4*>(ue + j)
                            : *reinterpret_cast<const floatx4*>(ie + (j - N_USERS * DIM));
  int o = (r < N_USERS) ? (r * 256 + d) : (OUT_I + (r - N_USERS) * 256 + d);
  __builtin_nontemporal_store(v, reinterpret_cast<floatx4*>(out + o));
}

// ---------------- fused hop: SpMM + LN + dropout + perturb + outputs ----------------
// one 64-lane wave per output row, lane = dim. Wave-uniform edge records are
// forced into SGPRs (readfirstlane) so mask test / col decode / address math
// run on the scalar pipe; the gather needs zero per-edge VALU address math.
template <int HOP>
__global__ __launch_bounds__(256) void k_hop(const int* __restrict__ rowstart,
                                             const uint2* __restrict__ packed,
                                             const float* __restrict__ Xa,
                                             const float* __restrict__ Xb,
                                             float* __restrict__ Xn,
                                             const float* __restrict__ gamma,
                                             const float* __restrict__ beta,
                                             float* __restrict__ out,
                                             uint32_t km0, uint32_t km1,
                                             uint32_t kp0, uint32_t kp1) {
  int gid = blockIdx.x * blockDim.x + threadIdx.x;
  int lane = threadIdx.x & 63;
  int r = __builtin_amdgcn_readfirstlane(gid >> 6);  // wave-uniform row -> SGPR
  if (r >= NTOT) return;
  int2 se = *reinterpret_cast<const int2*>(rowstart + r);  // {start, next start}
  int s = __builtin_amdgcn_readfirstlane(se.x);
  int e = __builtin_amdgcn_readfirstlane(se.y);
  constexpr uint32_t hb = 0x80000u << HOP;  // hop mask bit

  float acc0 = 0.0f, acc1 = 0.0f;
  int k = s;
  for (; k + 1 < e; k += 2) {
    uint2 pa = packed[k];
    uint2 pb = packed[k + 1];
    uint32_t pax = __builtin_amdgcn_readfirstlane(pa.x);
    uint32_t pbx = __builtin_amdgcn_readfirstlane(pb.x);
    if (pax & hb) {
      uint32_t c = pax & COLMASK;
      float vy = __uint_as_float(__builtin_amdgcn_readfirstlane(pa.y));
      const float* xp;
      if (HOP == 0) xp = (c < N_USERS) ? (Xa + c * DIM) : (Xb + (c - N_USERS) * DIM);
      else          xp = Xa + c * DIM;
      acc0 = fmaf(vy, xp[lane], acc0);
    }
    if (pbx & hb) {
      uint32_t c = pbx & COLMASK;
      float vy = __uint_as_float(__builtin_amdgcn_readfirstlane(pb.y));
      const float* xp;
      if (HOP == 0) xp = (c < N_USERS) ? (Xa + c * DIM) : (Xb + (c - N_USERS) * DIM);
      else          xp = Xa + c * DIM;
      acc1 = fmaf(vy, xp[lane], acc1);
    }
  }
  if (k < e) {
    uint2 pa = packed[k];
    uint32_t pax = __builtin_amdgcn_readfirstlane(pa.x);
    if (pax & hb) {
      uint32_t c = pax & COLMASK;
      float vy = __uint_as_float(__builtin_amdgcn_readfirstlane(pa.y));
      const float* xp;
      if (HOP == 0) xp = (c < N_USERS) ? (Xa + c * DIM) : (Xb + (c - N_USERS) * DIM);
      else          xp = Xa + c * DIM;
      acc0 = fmaf(vy, xp[lane], acc0);
    }
  }

  float x = acc0 + acc1;

  // layer norm: fused dual reduction (sum, sumsq) over the wave
  float s1 = x, s2 = x * x;
#pragma unroll
  for (int mm = 32; mm >= 1; mm >>= 1) {
    s1 += __shfl_xor(s1, mm, 64);
    s2 += __shfl_xor(s2, mm, 64);
  }
  float mu = s1 * (1.0f / 64.0f);
  float var = fmaxf(s2 * (1.0f / 64.0f) - mu * mu, 0.0f);
  x = (x - mu) * rsqrtf(var + 1e-5f) * gamma[lane] + beta[lane];

  // message dropout: keep iff uniform >= 0.1
  uint32_t j = (uint32_t)(r * DIM + lane);
  float um = u01f(rnd_bits(km0, km1, j));
  const float INV_KEEP = (float)(1.0 / 0.9);
  x = x * ((um >= 0.1f) ? INV_KEEP : 0.0f);

  // perturbation: normal via erfinv of uniform(lo, 1), row-normalized
  float un = u01f(rnd_bits(kp0, kp1, j));
  const float LO = __uint_as_float(0xBF7FFFFFu);  // nextafter(-1, 0)
  float val = un * 2.0f + LO;
  float nz = 0x1.6a09e6p+0f * erfinv_giles(val);   // sqrt(2) * erfinv
  float q2 = nz * nz;
#pragma unroll
  for (int mm = 32; mm >= 1; mm >>= 1) q2 += __shfl_xor(q2, mm, 64);
  float nrm = __builtin_sqrtf(q2);
  float nh = nz / (nrm + 1e-12f);
  float sg = (x > 0.0f) ? 1.0f : ((x < 0.0f) ? -1.0f : 0.0f);
  x = x + sg * nh * 0.03f;

  // write next-hop agg (cached: gathered next hop) + outputs (streamed, never re-read)
  Xn[r * DIM + lane] = x;
  constexpr int h1 = HOP + 1;
  if (r < N_USERS) {
    __builtin_nontemporal_store(x, &out[r * 256 + h1 * 64 + lane]);
    if (HOP == 0) __builtin_nontemporal_store(x, &out[OUT_CLU + r * 64 + lane]);
  } else {
    int i = r - N_USERS;
    __builtin_nontemporal_store(x, &out[OUT_I + i * 256 + h1 * 64 + lane]);
    if (HOP == 0) __builtin_nontemporal_store(x, &out[OUT_CLI + i * 64 + lane]);
  }
}

// ---------------- launch ----------------
extern "C" void kernel_launch(void* const* d_in, const int* in_sizes, int n_in,
                              void* d_out, int out_size, void* d_ws, size_t ws_size,
                              hipStream_t stream) {
  (void)in_sizes; (void)n_in; (void)out_size; (void)ws_size;
  const float* ue    = (const float*)d_in[0];
  const float* ie    = (const float*)d_in[1];
  const float* adjv  = (const float*)d_in[2];
  const float* gamma = (const float*)d_in[3];
  const float* beta  = (const float*)d_in[4];
  const int*   adji  = (const int*)d_in[5];
  const int* rows = adji;
  const int* cols = adji + NNZ;
  float* out = (float*)d_out;

  char* ws = (char*)d_ws;
  size_t off = 0;
  auto alloc = [&](size_t bytes) -> void* {
    void* p = ws + off;
    off += (bytes + 255) & ~(size_t)255;
    return p;
  };
  float* aggA   = (float*)alloc(sizeof(float) * NTOT * DIM);
  float* aggB   = (float*)alloc(sizeof(float) * NTOT * DIM);
  int*   cnt    = (int*)alloc(sizeof(int) * NTOT);
  int*   rowst  = (int*)alloc(sizeof(int) * (NTOT + 1));
  int*   gfill  = (int*)alloc(sizeof(int) * NB);
  int*   bsum   = (int*)alloc(sizeof(int) * 512);
  uint2* packed = (uint2*)alloc(sizeof(uint2) * NNZ);
  uint2* staging = (uint2*)aggB;  // alias: aggB first written by hop 0 output, staging dead by then

  // host-side key derivation: kh = fold_in(key(42), hop); (ke,km,kp) = split(kh, 3)
  uint32_t K[3][6];
  for (uint32_t h = 0; h < 3; h++) {
    uint32_t h0, h1;
    tf2x32(0u, 42u, 0u, h, h0, h1);
    tf2x32(h0, h1, 0u, 0u, K[h][0], K[h][1]);  // ke
    tf2x32(h0, h1, 0u, 1u, K[h][2], K[h][3]);  // km
    tf2x32(h0, h1, 0u, 2u, K[h][4], K[h][5]);  // kp
  }

  const int nbE = (NNZ + 255) / 256;
  const int nb1 = (NTOT + 1023) / 1024;  // 293
  (void)hipMemsetAsync(cnt, 0, sizeof(int) * NTOT, stream);
  k_hist<<<nbE, 256, 0, stream>>>(rows, cnt, NNZ);
  k_scan1<<<nb1, 256, 0, stream>>>(cnt, rowst, bsum, NTOT);
  k_scan2<<<1, 512, 0, stream>>>(bsum, nb1);
  k_scan3<<<(NTOT + 256) / 256, 256, 0, stream>>>(rowst, bsum, NTOT);
  k_binit<<<(NB + 255) / 256, 256, 0, stream>>>(rowst, gfill);
  k_bin<<<(NNZ + TILE - 1) / TILE, 256, 0, stream>>>(rows, cols, adjv, gfill, staging,
                                                     K[0][0], K[0][1], K[1][0], K[1][1],
                                                     K[2][0], K[2][1], NNZ);
  k_place<<<NB, 256, 0, stream>>>(rowst, gfill, staging, packed);
  k_init0<<<(NTOT * DIM / 4 + 255) / 256, 256, 0, stream>>>(ue, ie, out);

  const int nbH = (NTOT * DIM + 255) / 256;
  // hop 0: gather from ue/ie, write aggB
  k_hop<0><<<nbH, 256, 0, stream>>>(rowst, packed, ue, ie, aggB, gamma, beta, out,
                                    K[0][2], K[0][3], K[0][4], K[0][5]);
  // hop 1: gather from aggB, write aggA
  k_hop<1><<<nbH, 256, 0, stream>>>(rowst, packed, aggB, nullptr, aggA, gamma, beta, out,
                                    K[1][2], K[1][3], K[1][4], K[1][5]);
  // hop 2: gather from aggA, write aggB
  k_hop<2><<<nbH, 256, 0, stream>>>(rowst, packed, aggA, nullptr, aggB, gamma, beta, out,
                                    K[2][2], K[2][3], K[2][4], K[2][5]);
}

// Round 8
// 903.374 us; speedup vs baseline: 1.8342x; 1.0207x over previous
//
#include <hip/hip_runtime.h>
#include <stdint.h>

// ---------------- problem constants ----------------
#define N_USERS 100000
#define N_ITEMS 200000
#define NTOT    300000
#define DIM     64
#define NNZ     4000000

// output layout (floats)
#define OUT_I    25600000   // after users embs  (100000*4*64)
#define OUT_CLU  76800000   // after items embs  (+200000*4*64)
#define OUT_CLI  83200000   // after users cl    (+100000*64)

#define COLMASK  0x7FFFFu   // 19 bits (NTOT < 524288)

// bucketed CSR build
#define RPB   1024                      // rows per bucket (rowlocal fits 10 bits)
#define NB    ((NTOT + RPB - 1) / RPB)  // 293 buckets
#define TILE  4096                      // edges per phase-1 workgroup
#define HCAP  2500000                   // per-hop active-edge capacity (E[2M]+pad+margin)
#define RSTR  (NTOT + 1)                // rowstart stride per hop

typedef float floatx4 __attribute__((ext_vector_type(4)));
typedef uint32_t u32x4 __attribute__((ext_vector_type(4)));

// ---------------- threefry2x32 (20 rounds) ----------------
__host__ __device__ __forceinline__ void tf2x32(uint32_t k0, uint32_t k1,
                                                uint32_t x0, uint32_t x1,
                                                uint32_t& o0, uint32_t& o1) {
  uint32_t ks2 = k0 ^ k1 ^ 0x1BD11BDAu;
#define TFR(r) { x0 += x1; x1 = (x1 << (r)) | (x1 >> (32 - (r))); x1 ^= x0; }
  x0 += k0; x1 += k1;
  TFR(13) TFR(15) TFR(26) TFR(6)
  x0 += k1;  x1 += ks2 + 1u;
  TFR(17) TFR(29) TFR(16) TFR(24)
  x0 += ks2; x1 += k0 + 2u;
  TFR(13) TFR(15) TFR(26) TFR(6)
  x0 += k0;  x1 += k1 + 3u;
  TFR(17) TFR(29) TFR(16) TFR(24)
  x0 += k1;  x1 += ks2 + 4u;
  TFR(13) TFR(15) TFR(26) TFR(6)
  x0 += ks2; x1 += k0 + 5u;
#undef TFR
  o0 = x0; o1 = x1;
}

__device__ __forceinline__ uint32_t rnd_bits(uint32_t k0, uint32_t k1, uint32_t j) {
  uint32_t a, b;
  tf2x32(k0, k1, 0u, j, a, b);
  return a ^ b;
}

__device__ __forceinline__ float u01f(uint32_t bits) {
  return __uint_as_float((bits >> 9) | 0x3f800000u) - 1.0f;
}

// branchless single-precision erfinv (Giles 2010)
__device__ __forceinline__ float erfinv_giles(float x) {
  float w = -__logf((1.0f - x) * (1.0f + x));
  float wc = w - 2.5f;
  float p1 = 2.81022636e-08f;
  p1 = fmaf(p1, wc, 3.43273939e-07f);
  p1 = fmaf(p1, wc, -3.5233877e-06f);
  p1 = fmaf(p1, wc, -4.39150654e-06f);
  p1 = fmaf(p1, wc, 0.00021858087f);
  p1 = fmaf(p1, wc, -0.00125372503f);
  p1 = fmaf(p1, wc, -0.00417768164f);
  p1 = fmaf(p1, wc, 0.246640727f);
  p1 = fmaf(p1, wc, 1.50140941f);
  float wt = __builtin_sqrtf(w) - 3.0f;
  float p2 = -0.000200214257f;
  p2 = fmaf(p2, wt, 0.000100950558f);
  p2 = fmaf(p2, wt, 0.00134934322f);
  p2 = fmaf(p2, wt, -0.00367342844f);
  p2 = fmaf(p2, wt, 0.00573950773f);
  p2 = fmaf(p2, wt, -0.0076224613f);
  p2 = fmaf(p2, wt, 0.00943887047f);
  p2 = fmaf(p2, wt, 1.00167406f);
  p2 = fmaf(p2, wt, 2.83297682f);
  float p = (w < 5.0f) ? p1 : p2;
  return p * x;
}

// ---------------- scalar (SMEM) loads for wave-uniform data ----------------
// NOTE: early-clobber (=&s) is REQUIRED — multi-instruction asm writes outputs
// while the address input is still live (R7 fault was output/input overlap).
__device__ __forceinline__ void sload_pair(const int* p, int& a, int& b) {
  asm volatile("s_load_dword %0, %2, 0x0\n\t"
               "s_load_dword %1, %2, 0x4\n\t"
               "s_waitcnt lgkmcnt(0)"
               : "=&s"(a), "=&s"(b) : "s"(p));
}
// 4 records (32B, 16B-aligned)
__device__ __forceinline__ void sload_rec4(const uint2* p, u32x4& a, u32x4& b) {
  asm volatile("s_load_dwordx4 %0, %2, 0x0\n\t"
               "s_load_dwordx4 %1, %2, 0x10\n\t"
               "s_waitcnt lgkmcnt(0)"
               : "=&s"(a), "=&s"(b) : "s"(p));
}
// 2 records (16B, 16B-aligned)
__device__ __forceinline__ void sload_rec2(const uint2* p, u32x4& a) {
  asm volatile("s_load_dwordx4 %0, %1, 0x0\n\t"
               "s_waitcnt lgkmcnt(0)"
               : "=&s"(a) : "s"(p));
}

// ---------------- build: histogram (per-hop row counts + bucket sizes) ------
__global__ __launch_bounds__(256) void k_histB(const int* __restrict__ rows,
                                               int* __restrict__ cnt3,
                                               int* __restrict__ bsizes,
                                               uint32_t ke00, uint32_t ke01,
                                               uint32_t ke10, uint32_t ke11,
                                               uint32_t ke20, uint32_t ke21, int nnz) {
  __shared__ int hist[NB];
  int t = threadIdx.x;
  for (int i = t; i < NB; i += 256) hist[i] = 0;
  __syncthreads();
  int base = blockIdx.x * TILE;
#pragma unroll
  for (int i = 0; i < 16; i++) {
    int e = base + i * 256 + t;
    if (e < nnz) {
      int r = rows[e];
      uint32_t m0 = rnd_bits(ke00, ke01, (uint32_t)e) >> 31;
      uint32_t m1 = rnd_bits(ke10, ke11, (uint32_t)e) >> 31;
      uint32_t m2 = rnd_bits(ke20, ke21, (uint32_t)e) >> 31;
      if (m0) atomicAdd(&cnt3[r], 1);
      if (m1) atomicAdd(&cnt3[NTOT + r], 1);
      if (m2) atomicAdd(&cnt3[2 * NTOT + r], 1);
      atomicAdd(&hist[r >> 10], 1);
    }
  }
  __syncthreads();
  for (int i = t; i < NB; i += 256) {
    int c = hist[i];
    if (c) atomicAdd(&bsizes[i], c);
  }
}

// round per-row counts up to even (16B-aligned row starts in packed lists)
__global__ void k_even(const int* __restrict__ cnt3, int* __restrict__ cnt3e) {
  int i = blockIdx.x * blockDim.x + threadIdx.x;
  if (i < 3 * NTOT) cnt3e[i] = (cnt3[i] + 1) & ~1;
}

// single-block exclusive scan of bucket sizes -> bstart, gfill
__global__ void k_scanB(const int* __restrict__ bsizes, int* __restrict__ bstart,
                        int* __restrict__ gfill) {
  __shared__ int sm[512];
  int t = threadIdx.x;
  int v = (t < NB) ? bsizes[t] : 0;
  sm[t] = v;
  __syncthreads();
  for (int off = 1; off < 512; off <<= 1) {
    int y = (t >= off) ? sm[t - off] : 0;
    __syncthreads();
    sm[t] += y;
    __syncthreads();
  }
  if (t < NB) {
    int ex = sm[t] - v;
    bstart[t] = ex;
    gfill[t] = ex;
  }
}

// ---------------- per-hop row scans ----------------
__global__ void k_scan1(const int* __restrict__ cnt, int* __restrict__ rowstart,
                        int* __restrict__ bsum, int n) {
  __shared__ int sm[256];
  int t = threadIdx.x;
  int base = blockIdx.x * 1024 + t * 4;
  int v0 = (base     < n) ? cnt[base]     : 0;
  int v1 = (base + 1 < n) ? cnt[base + 1] : 0;
  int v2 = (base + 2 < n) ? cnt[base + 2] : 0;
  int v3 = (base + 3 < n) ? cnt[base + 3] : 0;
  int s = v0 + v1 + v2 + v3;
  sm[t] = s;
  __syncthreads();
  for (int off = 1; off < 256; off <<= 1) {
    int y = (t >= off) ? sm[t - off] : 0;
    __syncthreads();
    sm[t] += y;
    __syncthreads();
  }
  int ex = sm[t] - s;
  if (base     < n) rowstart[base]     = ex;
  if (base + 1 < n) rowstart[base + 1] = ex + v0;
  if (base + 2 < n) rowstart[base + 2] = ex + v0 + v1;
  if (base + 3 < n) rowstart[base + 3] = ex + v0 + v1 + v2;
  if (t == 255) bsum[blockIdx.x] = sm[255];
}

__global__ void k_scan2(int* bsum, int nb) {
  __shared__ int sm[512];
  int t = threadIdx.x;
  int v = (t < nb) ? bsum[t] : 0;
  sm[t] = v;
  __syncthreads();
  for (int off = 1; off < 512; off <<= 1) {
    int y = (t >= off) ? sm[t - off] : 0;
    __syncthreads();
    sm[t] += y;
    __syncthreads();
  }
  if (t < nb) bsum[t] = sm[t] - v;  // exclusive block offsets
}

__global__ void k_scan3(int* rowstart, const int* __restrict__ bsum,
                        const int* __restrict__ cnt, int n) {
  int i = blockIdx.x * blockDim.x + threadIdx.x;
  if (i < n) {
    int s = rowstart[i] + bsum[i >> 10];
    rowstart[i] = s;
    if (i == n - 1) rowstart[n] = s + cnt[i];  // sentinel = total (even)
  }
}

// ---------------- phase 1: bin edges into bucket runs ----------------
// staging record: w0 = col | m0<<19 | m1<<20 | m2<<21 | rowlocal<<22 ; w1 = val*2
__global__ __launch_bounds__(256) void k_bin(const int* __restrict__ rows,
                                             const int* __restrict__ cols,
                                             const float* __restrict__ adjv,
                                             int* __restrict__ gfill,
                                             uint2* __restrict__ staging,
                                             uint32_t ke00, uint32_t ke01,
                                             uint32_t ke10, uint32_t ke11,
                                             uint32_t ke20, uint32_t ke21, int nnz) {
  __shared__ int hist[NB];
  __shared__ int gb[NB];
  int t = threadIdx.x;
  for (int i = t; i < NB; i += 256) hist[i] = 0;
  __syncthreads();
  int base = blockIdx.x * TILE;

  uint32_t recx[16];
  float    recy[16];
  uint32_t bl[16];   // (bucket<<13) | localpos, 0xFFFFFFFF = invalid

#pragma unroll
  for (int i = 0; i < 16; i++) {
    int e = base + i * 256 + t;
    bl[i] = 0xFFFFFFFFu;
    if (e < nnz) {
      int r = rows[e];
      uint32_t c = (uint32_t)cols[e];
      uint32_t m0 = rnd_bits(ke00, ke01, (uint32_t)e) >> 31;
      uint32_t m1 = rnd_bits(ke10, ke11, (uint32_t)e) >> 31;
      uint32_t m2 = rnd_bits(ke20, ke21, (uint32_t)e) >> 31;
      recx[i] = c | (m0 << 19) | (m1 << 20) | (m2 << 21) | ((uint32_t)(r & (RPB - 1)) << 22);
      recy[i] = adjv[e] * 2.0f;
      int b = r >> 10;
      int lp = atomicAdd(&hist[b], 1);
      bl[i] = ((uint32_t)b << 13) | (uint32_t)lp;
    }
  }
  __syncthreads();
  for (int i = t; i < NB; i += 256) {
    int c = hist[i];
    gb[i] = c ? atomicAdd(&gfill[i], c) : 0;
  }
  __syncthreads();
#pragma unroll
  for (int i = 0; i < 16; i++) {
    if (bl[i] != 0xFFFFFFFFu) {
      int b  = (int)(bl[i] >> 13);
      int lp = (int)(bl[i] & 0x1FFFu);
      staging[gb[b] + lp] = make_uint2(recx[i], __float_as_uint(recy[i]));
    }
  }
}

// ---------------- phase 2: split staging into 3 per-hop active lists --------
__global__ __launch_bounds__(256) void k_place3(const int* __restrict__ bstart,
                                                const int* __restrict__ gfill,
                                                const int* __restrict__ rowst3,
                                                const uint2* __restrict__ staging,
                                                uint2* __restrict__ packed3) {
  __shared__ int rowfill[3][RPB];
  int b = blockIdx.x;
  int r0 = b << 10;
  int nr = min(RPB, NTOT - r0);
  for (int j = threadIdx.x; j < nr; j += 256) {
    rowfill[0][j] = rowst3[0 * RSTR + r0 + j];
    rowfill[1][j] = rowst3[1 * RSTR + r0 + j];
    rowfill[2][j] = rowst3[2 * RSTR + r0 + j];
  }
  __syncthreads();
  int s0 = bstart[b];
  int s1 = gfill[b];
  for (int i = s0 + (int)threadIdx.x; i < s1; i += 256) {
    uint2 rec = staging[i];
    int rl = (int)(rec.x >> 22);
    uint2 outrec = make_uint2(rec.x & COLMASK, rec.y);
    if (rec.x & (1u << 19)) {
      int pos = atomicAdd(&rowfill[0][rl], 1);
      packed3[0 * HCAP + pos] = outrec;
    }
    if (rec.x & (1u << 20)) {
      int pos = atomicAdd(&rowfill[1][rl], 1);
      packed3[1 * HCAP + pos] = outrec;
    }
    if (rec.x & (1u << 21)) {
      int pos = atomicAdd(&rowfill[2][rl], 1);
      packed3[2 * HCAP + pos] = outrec;
    }
  }
}

// write the <=1 pad record per row per hop: {col 0, val +0.0} contributes nothing
__global__ void k_pad(const int* __restrict__ cnt3, const int* __restrict__ rowst3,
                      uint2* __restrict__ packed3) {
  int r = blockIdx.x * blockDim.x + threadIdx.x;
  if (r >= NTOT) return;
#pragma unroll
  for (int h = 0; h < 3; h++) {
    int c = cnt3[h * NTOT + r];
    if (c & 1) packed3[h * HCAP + rowst3[h * RSTR + r] + c] = make_uint2(0u, 0u);
  }
}

// ---------------- hop-0 output slot only ----------------
__global__ void k_init0(const float* __restrict__ ue, const float* __restrict__ ie,
                        float* __restrict__ out) {
  int t = blockIdx.x * blockDim.x + threadIdx.x;
  if (t >= NTOT * DIM / 4) return;
  int j = t * 4;
  int r = j >> 6;
  int d = j & 63;
  floatx4 v = (r < N_USERS) ? *reinterpret_cast<const floatx4*>(ue + j)
                            : *reinterpret_cast<const floatx4*>(ie + (j - N_USERS * DIM));
  int o = (r < N_USERS) ? (r * 256 + d) : (OUT_I + (r - N_USERS) * 256 + d);
  __builtin_nontemporal_store(v, reinterpret_cast<floatx4*>(out + o));
}

// ---------------- fused hop: SpMM + LN + dropout + perturb + outputs --------
// one 64-lane wave per output row, lane = dim. Active-only edge list (even
// length, 16B-aligned starts); records fetched via s_load into SGPRs -> the
// per-edge VALU cost is one v_fmac with an SGPR operand.
template <int HOP>
__global__ __launch_bounds__(256) void k_hop(const int* __restrict__ rowst,
                                             const uint2* __restrict__ packed,
                                             const float* __restrict__ Xa,
                                             const float* __restrict__ Xb,
                                             float* __restrict__ Xn,
                                             const float* __restrict__ gamma,
                                             const float* __restrict__ beta,
                                             float* __restrict__ out,
                                             uint32_t km0, uint32_t km1,
                                             uint32_t kp0, uint32_t kp1) {
  int lane = threadIdx.x & 63;
  int r = __builtin_amdgcn_readfirstlane((int)(blockIdx.x * blockDim.x + threadIdx.x) >> 6);
  if (r >= NTOT) return;
  int s, e;
  sload_pair(rowst + r, s, e);
  // defensive clamps (SALU, free): degrade to wrong-zero rather than fault
  s = max(s, 0);
  e = min(e, HCAP);

#define XP(c) ((HOP == 0) ? (((c) < (uint32_t)N_USERS) ? (Xa + (c) * DIM)               \
                                                       : (Xb + ((c) - N_USERS) * DIM)) \
                          : (Xa + (c) * DIM))
  float acc0 = 0.0f, acc1 = 0.0f;
  int k = s;
  for (; k + 3 < e; k += 4) {
    u32x4 qa, qb;
    sload_rec4(packed + k, qa, qb);
    acc0 = fmaf(__uint_as_float(qa.y), XP(qa.x)[lane], acc0);
    acc1 = fmaf(__uint_as_float(qa.w), XP(qa.z)[lane], acc1);
    acc0 = fmaf(__uint_as_float(qb.y), XP(qb.x)[lane], acc0);
    acc1 = fmaf(__uint_as_float(qb.w), XP(qb.z)[lane], acc1);
  }
  if (k < e) {  // exactly 2 records remain (rows are even-length)
    u32x4 qa;
    sload_rec2(packed + k, qa);
    acc0 = fmaf(__uint_as_float(qa.y), XP(qa.x)[lane], acc0);
    acc1 = fmaf(__uint_as_float(qa.w), XP(qa.z)[lane], acc1);
  }
#undef XP

  float x = acc0 + acc1;

  // layer norm: fused dual reduction (sum, sumsq) over the wave
  float s1 = x, s2 = x * x;
#pragma unroll
  for (int mm = 32; mm >= 1; mm >>= 1) {
    s1 += __shfl_xor(s1, mm, 64);
    s2 += __shfl_xor(s2, mm, 64);
  }
  float mu = s1 * (1.0f / 64.0f);
  float var = fmaxf(s2 * (1.0f / 64.0f) - mu * mu, 0.0f);
  x = (x - mu) * rsqrtf(var + 1e-5f) * gamma[lane] + beta[lane];

  // message dropout: keep iff uniform >= 0.1
  uint32_t j = (uint32_t)(r * DIM + lane);
  float um = u01f(rnd_bits(km0, km1, j));
  const float INV_KEEP = (float)(1.0 / 0.9);
  x = x * ((um >= 0.1f) ? INV_KEEP : 0.0f);

  // perturbation: normal via erfinv of uniform(lo, 1), row-normalized
  float un = u01f(rnd_bits(kp0, kp1, j));
  const float LO = __uint_as_float(0xBF7FFFFFu);  // nextafter(-1, 0)
  float val = un * 2.0f + LO;
  float nz = 0x1.6a09e6p+0f * erfinv_giles(val);   // sqrt(2) * erfinv
  float q2 = nz * nz;
#pragma unroll
  for (int mm = 32; mm >= 1; mm >>= 1) q2 += __shfl_xor(q2, mm, 64);
  float nrm = __builtin_sqrtf(q2);
  float nh = nz / (nrm + 1e-12f);
  float sg = (x > 0.0f) ? 1.0f : ((x < 0.0f) ? -1.0f : 0.0f);
  x = x + sg * nh * 0.03f;

  // write next-hop agg (cached) + outputs (streamed, never re-read)
  Xn[r * DIM + lane] = x;
  constexpr int h1 = HOP + 1;
  if (r < N_USERS) {
    __builtin_nontemporal_store(x, &out[r * 256 + h1 * 64 + lane]);
    if (HOP == 0) __builtin_nontemporal_store(x, &out[OUT_CLU + r * 64 + lane]);
  } else {
    int i = r - N_USERS;
    __builtin_nontemporal_store(x, &out[OUT_I + i * 256 + h1 * 64 + lane]);
    if (HOP == 0) __builtin_nontemporal_store(x, &out[OUT_CLI + i * 64 + lane]);
  }
}

// ---------------- launch ----------------
extern "C" void kernel_launch(void* const* d_in, const int* in_sizes, int n_in,
                              void* d_out, int out_size, void* d_ws, size_t ws_size,
                              hipStream_t stream) {
  (void)in_sizes; (void)n_in; (void)out_size; (void)ws_size;
  const float* ue    = (const float*)d_in[0];
  const float* ie    = (const float*)d_in[1];
  const float* adjv  = (const float*)d_in[2];
  const float* gamma = (const float*)d_in[3];
  const float* beta  = (const float*)d_in[4];
  const int*   adji  = (const int*)d_in[5];
  const int* rows = adji;
  const int* cols = adji + NNZ;
  float* out = (float*)d_out;

  char* ws = (char*)d_ws;
  size_t off = 0;
  auto alloc = [&](size_t bytes) -> void* {
    void* p = ws + off;
    off += (bytes + 255) & ~(size_t)255;
    return p;
  };
  float* aggA    = (float*)alloc(sizeof(float) * NTOT * DIM);
  float* aggB    = (float*)alloc(sizeof(float) * NTOT * DIM);
  int*   cnt3    = (int*)alloc(sizeof(int) * 3 * NTOT);
  int*   cnt3e   = (int*)alloc(sizeof(int) * 3 * NTOT);
  int*   rowst3  = (int*)alloc(sizeof(int) * 3 * RSTR);
  int*   bsizes  = (int*)alloc(sizeof(int) * NB);
  int*   bstart  = (int*)alloc(sizeof(int) * NB);
  int*   gfill   = (int*)alloc(sizeof(int) * NB);
  int*   bsum    = (int*)alloc(sizeof(int) * 512);
  uint2* packed3 = (uint2*)alloc(sizeof(uint2) * 3 * HCAP);
  uint2* staging = (uint2*)aggB;  // alias: aggB first written by hop 0 output

  // host-side key derivation: kh = fold_in(key(42), hop); (ke,km,kp) = split(kh, 3)
  uint32_t K[3][6];
  for (uint32_t h = 0; h < 3; h++) {
    uint32_t h0, h1;
    tf2x32(0u, 42u, 0u, h, h0, h1);
    tf2x32(h0, h1, 0u, 0u, K[h][0], K[h][1]);  // ke
    tf2x32(h0, h1, 0u, 1u, K[h][2], K[h][3]);  // km
    tf2x32(h0, h1, 0u, 2u, K[h][4], K[h][5]);  // kp
  }

  const int nbT = (NNZ + TILE - 1) / TILE;   // 977 tiles
  const int nb1 = (NTOT + 1023) / 1024;      // 293
  (void)hipMemsetAsync(cnt3, 0, sizeof(int) * 3 * NTOT, stream);
  (void)hipMemsetAsync(bsizes, 0, sizeof(int) * NB, stream);

  k_histB<<<nbT, 256, 0, stream>>>(rows, cnt3, bsizes,
                                   K[0][0], K[0][1], K[1][0], K[1][1],
                                   K[2][0], K[2][1], NNZ);
  k_even<<<(3 * NTOT + 255) / 256, 256, 0, stream>>>(cnt3, cnt3e);
  k_scanB<<<1, 512, 0, stream>>>(bsizes, bstart, gfill);
  for (int h = 0; h < 3; h++) {
    k_scan1<<<nb1, 256, 0, stream>>>(cnt3e + h * NTOT, rowst3 + h * RSTR, bsum, NTOT);
    k_scan2<<<1, 512, 0, stream>>>(bsum, nb1);
    k_scan3<<<(NTOT + 255) / 256, 256, 0, stream>>>(rowst3 + h * RSTR, bsum,
                                                    cnt3e + h * NTOT, NTOT);
  }
  k_bin<<<nbT, 256, 0, stream>>>(rows, cols, adjv, gfill, staging,
                                 K[0][0], K[0][1], K[1][0], K[1][1],
                                 K[2][0], K[2][1], NNZ);
  k_place3<<<NB, 256, 0, stream>>>(bstart, gfill, rowst3, staging, packed3);
  k_pad<<<(NTOT + 255) / 256, 256, 0, stream>>>(cnt3, rowst3, packed3);
  k_init0<<<(NTOT * DIM / 4 + 255) / 256, 256, 0, stream>>>(ue, ie, out);

  const int nbH = (NTOT * DIM + 255) / 256;
  // hop 0: gather from ue/ie, write aggB (staging dead from here on)
  k_hop<0><<<nbH, 256, 0, stream>>>(rowst3 + 0 * RSTR, packed3 + 0 * HCAP, ue, ie,
                                    aggB, gamma, beta, out,
                                    K[0][2], K[0][3], K[0][4], K[0][5]);
  // hop 1: gather from aggB, write aggA
  k_hop<1><<<nbH, 256, 0, stream>>>(rowst3 + 1 * RSTR, packed3 + 1 * HCAP, aggB, nullptr,
                                    aggA, gamma, beta, out,
                                    K[1][2], K[1][3], K[1][4], K[1][5]);
  // hop 2: gather from aggA, write aggB
  k_hop<2><<<nbH, 256, 0, stream>>>(rowst3 + 2 * RSTR, packed3 + 2 * HCAP, aggA, nullptr,
                                    aggB, gamma, beta, out,
                                    K[2][2], K[2][3], K[2][4], K[2][5]);
}

// Round 9
// 653.875 us; speedup vs baseline: 2.5341x; 1.3816x over previous
//
#include <hip/hip_runtime.h>
#include <stdint.h>

// ---------------- problem constants ----------------
#define N_USERS 100000
#define N_ITEMS 200000
#define NTOT    300000
#define DIM     64
#define NNZ     4000000

// output layout (floats)
#define OUT_I    25600000   // after users embs  (100000*4*64)
#define OUT_CLU  76800000   // after items embs  (+200000*4*64)
#define OUT_CLI  83200000   // after users cl    (+100000*64)

#define COLMASK  0x7FFFFu   // 19 bits (NTOT < 524288)

// bucketed CSR build
#define RPB   1024                      // rows per bucket (rowlocal fits 10 bits)
#define NB    ((NTOT + RPB - 1) / RPB)  // 293 buckets
#define TILE  4096                      // edges per bin workgroup
#define BCAP  20480                     // per-bucket staging capacity (mean 13.6K, 58 sigma)
#define HCAP  2500000                   // per-hop active-edge capacity (~2M + pads + margin)

typedef float floatx4 __attribute__((ext_vector_type(4)));
typedef uint32_t u32x4 __attribute__((ext_vector_type(4)));

// ---------------- threefry2x32 (20 rounds) ----------------
__host__ __device__ __forceinline__ void tf2x32(uint32_t k0, uint32_t k1,
                                                uint32_t x0, uint32_t x1,
                                                uint32_t& o0, uint32_t& o1) {
  uint32_t ks2 = k0 ^ k1 ^ 0x1BD11BDAu;
#define TFR(r) { x0 += x1; x1 = (x1 << (r)) | (x1 >> (32 - (r))); x1 ^= x0; }
  x0 += k0; x1 += k1;
  TFR(13) TFR(15) TFR(26) TFR(6)
  x0 += k1;  x1 += ks2 + 1u;
  TFR(17) TFR(29) TFR(16) TFR(24)
  x0 += ks2; x1 += k0 + 2u;
  TFR(13) TFR(15) TFR(26) TFR(6)
  x0 += k0;  x1 += k1 + 3u;
  TFR(17) TFR(29) TFR(16) TFR(24)
  x0 += k1;  x1 += ks2 + 4u;
  TFR(13) TFR(15) TFR(26) TFR(6)
  x0 += ks2; x1 += k0 + 5u;
#undef TFR
  o0 = x0; o1 = x1;
}

__device__ __forceinline__ uint32_t rnd_bits(uint32_t k0, uint32_t k1, uint32_t j) {
  uint32_t a, b;
  tf2x32(k0, k1, 0u, j, a, b);
  return a ^ b;
}

__device__ __forceinline__ float u01f(uint32_t bits) {
  return __uint_as_float((bits >> 9) | 0x3f800000u) - 1.0f;
}

// branchless single-precision erfinv (Giles 2010)
__device__ __forceinline__ float erfinv_giles(float x) {
  float w = -__logf((1.0f - x) * (1.0f + x));
  float wc = w - 2.5f;
  float p1 = 2.81022636e-08f;
  p1 = fmaf(p1, wc, 3.43273939e-07f);
  p1 = fmaf(p1, wc, -3.5233877e-06f);
  p1 = fmaf(p1, wc, -4.39150654e-06f);
  p1 = fmaf(p1, wc, 0.00021858087f);
  p1 = fmaf(p1, wc, -0.00125372503f);
  p1 = fmaf(p1, wc, -0.00417768164f);
  p1 = fmaf(p1, wc, 0.246640727f);
  p1 = fmaf(p1, wc, 1.50140941f);
  float wt = __builtin_sqrtf(w) - 3.0f;
  float p2 = -0.000200214257f;
  p2 = fmaf(p2, wt, 0.000100950558f);
  p2 = fmaf(p2, wt, 0.00134934322f);
  p2 = fmaf(p2, wt, -0.00367342844f);
  p2 = fmaf(p2, wt, 0.00573950773f);
  p2 = fmaf(p2, wt, -0.0076224613f);
  p2 = fmaf(p2, wt, 0.00943887047f);
  p2 = fmaf(p2, wt, 1.00167406f);
  p2 = fmaf(p2, wt, 2.83297682f);
  float p = (w < 5.0f) ? p1 : p2;
  return p * x;
}

// ---------------- scalar (SMEM) loads for wave-uniform data ----------------
// early-clobber (=&s) REQUIRED: outputs written while address input still live.
__device__ __forceinline__ void sload_se(const int2* p, int& s, int& e) {
  uint64_t r;
  asm volatile("s_load_dwordx2 %0, %1, 0x0\n\t"
               "s_waitcnt lgkmcnt(0)"
               : "=&s"(r) : "s"(p));
  s = (int)(uint32_t)r;
  e = (int)(uint32_t)(r >> 32);
}
// 8 records (64B, 16B-aligned start)
__device__ __forceinline__ void sload_rec8(const uint2* p, u32x4& a, u32x4& b,
                                           u32x4& c, u32x4& d) {
  asm volatile("s_load_dwordx4 %0, %4, 0x0\n\t"
               "s_load_dwordx4 %1, %4, 0x10\n\t"
               "s_load_dwordx4 %2, %4, 0x20\n\t"
               "s_load_dwordx4 %3, %4, 0x30\n\t"
               "s_waitcnt lgkmcnt(0)"
               : "=&s"(a), "=&s"(b), "=&s"(c), "=&s"(d) : "s"(p));
}
// 2 records (16B, 16B-aligned)
__device__ __forceinline__ void sload_rec2(const uint2* p, u32x4& a) {
  asm volatile("s_load_dwordx4 %0, %1, 0x0\n\t"
               "s_waitcnt lgkmcnt(0)"
               : "=&s"(a) : "s"(p));
}

// ---------------- phase 1: bin edges into per-bucket staging runs -----------
// staging record: w0 = col | m0<<19 | m1<<20 | m2<<21 | rowlocal<<22 ; w1 = val*2
__global__ __launch_bounds__(256) void k_bin(const int* __restrict__ rows,
                                             const int* __restrict__ cols,
                                             const float* __restrict__ adjv,
                                             int* __restrict__ gcount,
                                             uint2* __restrict__ staging,
                                             uint32_t ke00, uint32_t ke01,
                                             uint32_t ke10, uint32_t ke11,
                                             uint32_t ke20, uint32_t ke21, int nnz) {
  __shared__ int hist[NB];
  __shared__ int gb[NB];
  int t = threadIdx.x;
  for (int i = t; i < NB; i += 256) hist[i] = 0;
  __syncthreads();
  int base = blockIdx.x * TILE;

  uint32_t recx[16];
  float    recy[16];
  uint32_t bl[16];   // (bucket<<13) | localpos, 0xFFFFFFFF = invalid

#pragma unroll
  for (int i = 0; i < 16; i++) {
    int e = base + i * 256 + t;
    bl[i] = 0xFFFFFFFFu;
    if (e < nnz) {
      int r = rows[e];
      uint32_t c = (uint32_t)cols[e];
      uint32_t m0 = rnd_bits(ke00, ke01, (uint32_t)e) >> 31;
      uint32_t m1 = rnd_bits(ke10, ke11, (uint32_t)e) >> 31;
      uint32_t m2 = rnd_bits(ke20, ke21, (uint32_t)e) >> 31;
      recx[i] = c | (m0 << 19) | (m1 << 20) | (m2 << 21) | ((uint32_t)(r & (RPB - 1)) << 22);
      recy[i] = adjv[e] * 2.0f;
      int b = r >> 10;
      int lp = atomicAdd(&hist[b], 1);
      bl[i] = ((uint32_t)b << 13) | (uint32_t)lp;
    }
  }
  __syncthreads();
  for (int i = t; i < NB; i += 256) {
    int c = hist[i];
    gb[i] = c ? atomicAdd(&gcount[i], c) : 0;
  }
  __syncthreads();
#pragma unroll
  for (int i = 0; i < 16; i++) {
    if (bl[i] != 0xFFFFFFFFu) {
      int b  = (int)(bl[i] >> 13);
      int lp = (int)(bl[i] & 0x1FFFu);
      staging[(size_t)b * BCAP + gb[b] + lp] = make_uint2(recx[i], __float_as_uint(recy[i]));
    }
  }
}

// ---------------- phase 2: per-bucket count/scan/reserve/scatter ------------
// Produces, per hop: packed active list (even-padded rows, {0,+0} pads) and
// rowse3[h][r] = {start, start+evened_count}. Rows need no global ordering.
__global__ __launch_bounds__(256) void k_place3(const int* __restrict__ gcount,
                                                const uint2* __restrict__ staging,
                                                uint2* __restrict__ packed3,
                                                int2* __restrict__ rowse3,
                                                int* __restrict__ gtail) {
  __shared__ int cnt[3][RPB];
  __shared__ int off[3][RPB];
  __shared__ int sm[256];
  __shared__ int gbh[3];
  int b = blockIdx.x;
  int t = threadIdx.x;
  int r0 = b << 10;
  for (int j = t; j < RPB; j += 256) { cnt[0][j] = 0; cnt[1][j] = 0; cnt[2][j] = 0; }
  __syncthreads();
  int ln = gcount[b];
  const uint2* run = staging + (size_t)b * BCAP;

  // pass A: per-row per-hop counts
  for (int i = t; i < ln; i += 256) {
    uint32_t w = run[i].x;
    int rl = (int)(w >> 22);
    if (w & (1u << 19)) atomicAdd(&cnt[0][rl], 1);
    if (w & (1u << 20)) atomicAdd(&cnt[1][rl], 1);
    if (w & (1u << 21)) atomicAdd(&cnt[2][rl], 1);
  }
  __syncthreads();

  // pass B: evened exclusive scan per hop + global reservation
  for (int h = 0; h < 3; h++) {
    int j0 = t * 4;
    int c0 = cnt[h][j0], c1 = cnt[h][j0 + 1], c2 = cnt[h][j0 + 2], c3 = cnt[h][j0 + 3];
    int e0 = (c0 + 1) & ~1, e1 = (c1 + 1) & ~1, e2 = (c2 + 1) & ~1, e3 = (c3 + 1) & ~1;
    int s4 = e0 + e1 + e2 + e3;
    sm[t] = s4;
    __syncthreads();
    for (int o2 = 1; o2 < 256; o2 <<= 1) {
      int y = (t >= o2) ? sm[t - o2] : 0;
      __syncthreads();
      sm[t] += y;
      __syncthreads();
    }
    int ex = sm[t] - s4;
    off[h][j0]     = ex;
    off[h][j0 + 1] = ex + e0;
    off[h][j0 + 2] = ex + e0 + e1;
    off[h][j0 + 3] = ex + e0 + e1 + e2;
    if (t == 255) gbh[h] = atomicAdd(&gtail[h], sm[255]);
    __syncthreads();
  }

  // pass B2: rowse + pad records + absolute fill positions
  int nr = min(RPB, NTOT - r0);
  for (int h = 0; h < 3; h++) {
    int gb = gbh[h];
    for (int j = t; j < RPB; j += 256) {
      int raw = cnt[h][j];
      int start = gb + off[h][j];
      off[h][j] = start;  // absolute scatter cursor
      if (j < nr) {
        rowse3[h * NTOT + r0 + j] = make_int2(start, start + ((raw + 1) & ~1));
        if (raw & 1) packed3[(size_t)h * HCAP + start + raw] = make_uint2(0u, 0u);
      }
    }
  }
  __syncthreads();

  // pass C: scatter records to per-hop lists
  for (int i = t; i < ln; i += 256) {
    uint2 rec = run[i];
    int rl = (int)(rec.x >> 22);
    uint2 orec = make_uint2(rec.x & COLMASK, rec.y);
    if (rec.x & (1u << 19)) { int p = atomicAdd(&off[0][rl], 1); packed3[0 * (size_t)HCAP + p] = orec; }
    if (rec.x & (1u << 20)) { int p = atomicAdd(&off[1][rl], 1); packed3[1 * (size_t)HCAP + p] = orec; }
    if (rec.x & (1u << 21)) { int p = atomicAdd(&off[2][rl], 1); packed3[2 * (size_t)HCAP + p] = orec; }
  }
}

// ---------------- hop-0 output slot only ----------------
__global__ void k_init0(const float* __restrict__ ue, const float* __restrict__ ie,
                        float* __restrict__ out) {
  int t = blockIdx.x * blockDim.x + threadIdx.x;
  if (t >= NTOT * DIM / 4) return;
  int j = t * 4;
  int r = j >> 6;
  int d = j & 63;
  floatx4 v = (r < N_USERS) ? *reinterpret_cast<const floatx4*>(ue + j)
                            : *reinterpret_cast<const floatx4*>(ie + (j - N_USERS * DIM));
  int o = (r < N_USERS) ? (r * 256 + d) : (OUT_I + (r - N_USERS) * 256 + d);
  __builtin_nontemporal_store(v, reinterpret_cast<floatx4*>(out + o));
}

// ---------------- fused hop: SpMM + LN + dropout + perturb + outputs --------
// one 64-lane wave per row, lane = dim. Active-only even-padded edge list;
// records via s_load into SGPRs; 8-record unroll, 4 accumulators for ILP.
template <int HOP>
__global__ __launch_bounds__(256) void k_hop(const int2* __restrict__ rowse,
                                             const uint2* __restrict__ packed,
                                             const float* __restrict__ Xa,
                                             const float* __restrict__ Xb,
                                             float* __restrict__ Xn,
                                             const float* __restrict__ gamma,
                                             const float* __restrict__ beta,
                                             float* __restrict__ out,
                                             uint32_t km0, uint32_t km1,
                                             uint32_t kp0, uint32_t kp1) {
  int lane = threadIdx.x & 63;
  int r = __builtin_amdgcn_readfirstlane((int)(blockIdx.x * blockDim.x + threadIdx.x) >> 6);
  if (r >= NTOT) return;
  int s, e;
  sload_se(rowse + r, s, e);
  s = max(s, 0);
  e = min(e, HCAP);

#define XP(c) ((HOP == 0) ? (((c) < (uint32_t)N_USERS) ? (Xa + (c) * DIM)               \
                                                       : (Xb + ((c) - N_USERS) * DIM)) \
                          : (Xa + (c) * DIM))
  float acc0 = 0.0f, acc1 = 0.0f, acc2 = 0.0f, acc3 = 0.0f;
  int k = s;
  for (; k + 7 < e; k += 8) {
    u32x4 qa, qb, qc, qd;
    sload_rec8(packed + k, qa, qb, qc, qd);
    acc0 = fmaf(__uint_as_float(qa.y), XP(qa.x)[lane], acc0);
    acc1 = fmaf(__uint_as_float(qa.w), XP(qa.z)[lane], acc1);
    acc2 = fmaf(__uint_as_float(qb.y), XP(qb.x)[lane], acc2);
    acc3 = fmaf(__uint_as_float(qb.w), XP(qb.z)[lane], acc3);
    acc0 = fmaf(__uint_as_float(qc.y), XP(qc.x)[lane], acc0);
    acc1 = fmaf(__uint_as_float(qc.w), XP(qc.z)[lane], acc1);
    acc2 = fmaf(__uint_as_float(qd.y), XP(qd.x)[lane], acc2);
    acc3 = fmaf(__uint_as_float(qd.w), XP(qd.z)[lane], acc3);
  }
  for (; k + 1 < e; k += 2) {
    u32x4 qa;
    sload_rec2(packed + k, qa);
    acc0 = fmaf(__uint_as_float(qa.y), XP(qa.x)[lane], acc0);
    acc1 = fmaf(__uint_as_float(qa.w), XP(qa.z)[lane], acc1);
  }
#undef XP

  float x = (acc0 + acc1) + (acc2 + acc3);

  // layer norm: fused dual reduction (sum, sumsq) over the wave
  float s1 = x, s2 = x * x;
#pragma unroll
  for (int mm = 32; mm >= 1; mm >>= 1) {
    s1 += __shfl_xor(s1, mm, 64);
    s2 += __shfl_xor(s2, mm, 64);
  }
  float mu = s1 * (1.0f / 64.0f);
  float var = fmaxf(s2 * (1.0f / 64.0f) - mu * mu, 0.0f);
  x = (x - mu) * rsqrtf(var + 1e-5f) * gamma[lane] + beta[lane];

  // message dropout: keep iff uniform >= 0.1
  uint32_t j = (uint32_t)(r * DIM + lane);
  float um = u01f(rnd_bits(km0, km1, j));
  const float INV_KEEP = (float)(1.0 / 0.9);
  x = x * ((um >= 0.1f) ? INV_KEEP : 0.0f);

  // perturbation: normal via erfinv of uniform(lo, 1), row-normalized
  float un = u01f(rnd_bits(kp0, kp1, j));
  const float LO = __uint_as_float(0xBF7FFFFFu);  // nextafter(-1, 0)
  float val = un * 2.0f + LO;
  float nz = 0x1.6a09e6p+0f * erfinv_giles(val);   // sqrt(2) * erfinv
  float q2 = nz * nz;
#pragma unroll
  for (int mm = 32; mm >= 1; mm >>= 1) q2 += __shfl_xor(q2, mm, 64);
  float nrm = __builtin_sqrtf(q2);
  float nh = nz / (nrm + 1e-12f);
  float sg = (x > 0.0f) ? 1.0f : ((x < 0.0f) ? -1.0f : 0.0f);
  x = x + sg * nh * 0.03f;

  // write next-hop agg (cached) + outputs (streamed, never re-read)
  Xn[r * DIM + lane] = x;
  constexpr int h1 = HOP + 1;
  if (r < N_USERS) {
    __builtin_nontemporal_store(x, &out[r * 256 + h1 * 64 + lane]);
    if (HOP == 0) __builtin_nontemporal_store(x, &out[OUT_CLU + r * 64 + lane]);
  } else {
    int i = r - N_USERS;
    __builtin_nontemporal_store(x, &out[OUT_I + i * 256 + h1 * 64 + lane]);
    if (HOP == 0) __builtin_nontemporal_store(x, &out[OUT_CLI + i * 64 + lane]);
  }
}

// ---------------- launch ----------------
extern "C" void kernel_launch(void* const* d_in, const int* in_sizes, int n_in,
                              void* d_out, int out_size, void* d_ws, size_t ws_size,
                              hipStream_t stream) {
  (void)in_sizes; (void)n_in; (void)out_size; (void)ws_size;
  const float* ue    = (const float*)d_in[0];
  const float* ie    = (const float*)d_in[1];
  const float* adjv  = (const float*)d_in[2];
  const float* gamma = (const float*)d_in[3];
  const float* beta  = (const float*)d_in[4];
  const int*   adji  = (const int*)d_in[5];
  const int* rows = adji;
  const int* cols = adji + NNZ;
  float* out = (float*)d_out;

  char* ws = (char*)d_ws;
  size_t off = 0;
  auto alloc = [&](size_t bytes) -> void* {
    void* p = ws + off;
    off += (bytes + 255) & ~(size_t)255;
    return p;
  };
  float* aggA    = (float*)alloc(sizeof(float) * NTOT * DIM);
  float* aggB    = (float*)alloc(sizeof(float) * NTOT * DIM);
  int*   gcount  = (int*)alloc(sizeof(int) * NB);
  int*   gtail   = (int*)alloc(sizeof(int) * 4);
  int2*  rowse3  = (int2*)alloc(sizeof(int2) * 3 * NTOT);
  uint2* staging = (uint2*)alloc(sizeof(uint2) * (size_t)NB * BCAP);
  uint2* packed3 = (uint2*)alloc(sizeof(uint2) * 3 * (size_t)HCAP);

  // host-side key derivation: kh = fold_in(key(42), hop); (ke,km,kp) = split(kh, 3)
  uint32_t K[3][6];
  for (uint32_t h = 0; h < 3; h++) {
    uint32_t h0, h1;
    tf2x32(0u, 42u, 0u, h, h0, h1);
    tf2x32(h0, h1, 0u, 0u, K[h][0], K[h][1]);  // ke
    tf2x32(h0, h1, 0u, 1u, K[h][2], K[h][3]);  // km
    tf2x32(h0, h1, 0u, 2u, K[h][4], K[h][5]);  // kp
  }

  const int nbT = (NNZ + TILE - 1) / TILE;   // 977 tiles
  (void)hipMemsetAsync(gcount, 0, sizeof(int) * NB, stream);
  (void)hipMemsetAsync(gtail, 0, sizeof(int) * 4, stream);

  k_bin<<<nbT, 256, 0, stream>>>(rows, cols, adjv, gcount, staging,
                                 K[0][0], K[0][1], K[1][0], K[1][1],
                                 K[2][0], K[2][1], NNZ);
  k_place3<<<NB, 256, 0, stream>>>(gcount, staging, packed3, rowse3, gtail);
  k_init0<<<(NTOT * DIM / 4 + 255) / 256, 256, 0, stream>>>(ue, ie, out);

  const int nbH = (NTOT * DIM + 255) / 256;
  // hop 0: gather from ue/ie, write aggB
  k_hop<0><<<nbH, 256, 0, stream>>>(rowse3 + 0 * NTOT, packed3 + 0 * (size_t)HCAP, ue, ie,
                                    aggB, gamma, beta, out,
                                    K[0][2], K[0][3], K[0][4], K[0][5]);
  // hop 1: gather from aggB, write aggA
  k_hop<1><<<nbH, 256, 0, stream>>>(rowse3 + 1 * NTOT, packed3 + 1 * (size_t)HCAP, aggB, nullptr,
                                    aggA, gamma, beta, out,
                                    K[1][2], K[1][3], K[1][4], K[1][5]);
  // hop 2: gather from aggA, write aggB
  k_hop<2><<<nbH, 256, 0, stream>>>(rowse3 + 2 * NTOT, packed3 + 2 * (size_t)HCAP, aggA, nullptr,
                                    aggB, gamma, beta, out,
                                    K[2][2], K[2][3], K[2][4], K[2][5]);
}

// Round 10
// 643.663 us; speedup vs baseline: 2.5743x; 1.0159x over previous
//
#include <hip/hip_runtime.h>
#include <stdint.h>

// ---------------- problem constants ----------------
#define N_USERS 100000
#define N_ITEMS 200000
#define NTOT    300000
#define DIM     64
#define NNZ     4000000

// output layout (floats)
#define OUT_I    25600000   // after users embs  (100000*4*64)
#define OUT_CLU  76800000   // after items embs  (+200000*4*64)
#define OUT_CLI  83200000   // after users cl    (+100000*64)

#define COLMASK  0x7FFFFu   // 19 bits (NTOT < 524288)

// bucketed CSR build
#define RPB   1024                      // rows per bucket (rowlocal fits 10 bits)
#define NB    ((NTOT + RPB - 1) / RPB)  // 293 buckets
#define TILE  4096                      // edges per bin workgroup
#define BCAP  20480                     // per-bucket staging capacity (mean 13.6K, 58 sigma)
#define HCAP  2500000                   // per-hop active-edge capacity (~2M + pads + margin)

typedef float floatx4 __attribute__((ext_vector_type(4)));
typedef uint32_t u32x4 __attribute__((ext_vector_type(4)));
typedef unsigned short ushortx4 __attribute__((ext_vector_type(4)));

// ---------------- threefry2x32 (20 rounds) ----------------
__host__ __device__ __forceinline__ void tf2x32(uint32_t k0, uint32_t k1,
                                                uint32_t x0, uint32_t x1,
                                                uint32_t& o0, uint32_t& o1) {
  uint32_t ks2 = k0 ^ k1 ^ 0x1BD11BDAu;
#define TFR(r) { x0 += x1; x1 = (x1 << (r)) | (x1 >> (32 - (r))); x1 ^= x0; }
  x0 += k0; x1 += k1;
  TFR(13) TFR(15) TFR(26) TFR(6)
  x0 += k1;  x1 += ks2 + 1u;
  TFR(17) TFR(29) TFR(16) TFR(24)
  x0 += ks2; x1 += k0 + 2u;
  TFR(13) TFR(15) TFR(26) TFR(6)
  x0 += k0;  x1 += k1 + 3u;
  TFR(17) TFR(29) TFR(16) TFR(24)
  x0 += k1;  x1 += ks2 + 4u;
  TFR(13) TFR(15) TFR(26) TFR(6)
  x0 += ks2; x1 += k0 + 5u;
#undef TFR
  o0 = x0; o1 = x1;
}

__device__ __forceinline__ uint32_t rnd_bits(uint32_t k0, uint32_t k1, uint32_t j) {
  uint32_t a, b;
  tf2x32(k0, k1, 0u, j, a, b);
  return a ^ b;
}

__device__ __forceinline__ float u01f(uint32_t bits) {
  return __uint_as_float((bits >> 9) | 0x3f800000u) - 1.0f;
}

// fp32 -> bf16 with round-to-nearest-even
__device__ __forceinline__ unsigned short f2bf(float f) {
  uint32_t u = __float_as_uint(f);
  return (unsigned short)((u + 0x7FFFu + ((u >> 16) & 1u)) >> 16);
}

// branchless single-precision erfinv (Giles 2010)
__device__ __forceinline__ float erfinv_giles(float x) {
  float w = -__logf((1.0f - x) * (1.0f + x));
  float wc = w - 2.5f;
  float p1 = 2.81022636e-08f;
  p1 = fmaf(p1, wc, 3.43273939e-07f);
  p1 = fmaf(p1, wc, -3.5233877e-06f);
  p1 = fmaf(p1, wc, -4.39150654e-06f);
  p1 = fmaf(p1, wc, 0.00021858087f);
  p1 = fmaf(p1, wc, -0.00125372503f);
  p1 = fmaf(p1, wc, -0.00417768164f);
  p1 = fmaf(p1, wc, 0.246640727f);
  p1 = fmaf(p1, wc, 1.50140941f);
  float wt = __builtin_sqrtf(w) - 3.0f;
  float p2 = -0.000200214257f;
  p2 = fmaf(p2, wt, 0.000100950558f);
  p2 = fmaf(p2, wt, 0.00134934322f);
  p2 = fmaf(p2, wt, -0.00367342844f);
  p2 = fmaf(p2, wt, 0.00573950773f);
  p2 = fmaf(p2, wt, -0.0076224613f);
  p2 = fmaf(p2, wt, 0.00943887047f);
  p2 = fmaf(p2, wt, 1.00167406f);
  p2 = fmaf(p2, wt, 2.83297682f);
  float p = (w < 5.0f) ? p1 : p2;
  return p * x;
}

// ---------------- scalar (SMEM) loads for wave-uniform data ----------------
// early-clobber (=&s) REQUIRED: outputs written while address input still live.
__device__ __forceinline__ void sload_se(const int2* p, int& s, int& e) {
  uint64_t r;
  asm volatile("s_load_dwordx2 %0, %1, 0x0\n\t"
               "s_waitcnt lgkmcnt(0)"
               : "=&s"(r) : "s"(p));
  s = (int)(uint32_t)r;
  e = (int)(uint32_t)(r >> 32);
}
// 8 records (64B, 16B-aligned start)
__device__ __forceinline__ void sload_rec8(const uint2* p, u32x4& a, u32x4& b,
                                           u32x4& c, u32x4& d) {
  asm volatile("s_load_dwordx4 %0, %4, 0x0\n\t"
               "s_load_dwordx4 %1, %4, 0x10\n\t"
               "s_load_dwordx4 %2, %4, 0x20\n\t"
               "s_load_dwordx4 %3, %4, 0x30\n\t"
               "s_waitcnt lgkmcnt(0)"
               : "=&s"(a), "=&s"(b), "=&s"(c), "=&s"(d) : "s"(p));
}
// 2 records (16B, 16B-aligned)
__device__ __forceinline__ void sload_rec2(const uint2* p, u32x4& a) {
  asm volatile("s_load_dwordx4 %0, %1, 0x0\n\t"
               "s_waitcnt lgkmcnt(0)"
               : "=&s"(a) : "s"(p));
}

// ---------------- phase 1: bin edges into per-bucket staging runs -----------
// staging record: w0 = col | m0<<19 | m1<<20 | m2<<21 | rowlocal<<22 ; w1 = val*2
__global__ __launch_bounds__(256) void k_bin(const int* __restrict__ rows,
                                             const int* __restrict__ cols,
                                             const float* __restrict__ adjv,
                                             int* __restrict__ gcount,
                                             uint2* __restrict__ staging,
                                             uint32_t ke00, uint32_t ke01,
                                             uint32_t ke10, uint32_t ke11,
                                             uint32_t ke20, uint32_t ke21, int nnz) {
  __shared__ int hist[NB];
  __shared__ int gb[NB];
  int t = threadIdx.x;
  for (int i = t; i < NB; i += 256) hist[i] = 0;
  __syncthreads();
  int base = blockIdx.x * TILE;

  uint32_t recx[16];
  float    recy[16];
  uint32_t bl[16];   // (bucket<<13) | localpos, 0xFFFFFFFF = invalid

#pragma unroll
  for (int i = 0; i < 16; i++) {
    int e = base + i * 256 + t;
    bl[i] = 0xFFFFFFFFu;
    if (e < nnz) {
      int r = rows[e];
      uint32_t c = (uint32_t)cols[e];
      uint32_t m0 = rnd_bits(ke00, ke01, (uint32_t)e) >> 31;
      uint32_t m1 = rnd_bits(ke10, ke11, (uint32_t)e) >> 31;
      uint32_t m2 = rnd_bits(ke20, ke21, (uint32_t)e) >> 31;
      recx[i] = c | (m0 << 19) | (m1 << 20) | (m2 << 21) | ((uint32_t)(r & (RPB - 1)) << 22);
      recy[i] = adjv[e] * 2.0f;
      int b = r >> 10;
      int lp = atomicAdd(&hist[b], 1);
      bl[i] = ((uint32_t)b << 13) | (uint32_t)lp;
    }
  }
  __syncthreads();
  for (int i = t; i < NB; i += 256) {
    int c = hist[i];
    gb[i] = c ? atomicAdd(&gcount[i], c) : 0;
  }
  __syncthreads();
#pragma unroll
  for (int i = 0; i < 16; i++) {
    if (bl[i] != 0xFFFFFFFFu) {
      int b  = (int)(bl[i] >> 13);
      int lp = (int)(bl[i] & 0x1FFFu);
      staging[(size_t)b * BCAP + gb[b] + lp] = make_uint2(recx[i], __float_as_uint(recy[i]));
    }
  }
}

// ---------------- phase 2: per-bucket count/scan/reserve/scatter ------------
__global__ __launch_bounds__(256) void k_place3(const int* __restrict__ gcount,
                                                const uint2* __restrict__ staging,
                                                uint2* __restrict__ packed3,
                                                int2* __restrict__ rowse3,
                                                int* __restrict__ gtail) {
  __shared__ int cnt[3][RPB];
  __shared__ int off[3][RPB];
  __shared__ int sm[256];
  __shared__ int gbh[3];
  int b = blockIdx.x;
  int t = threadIdx.x;
  int r0 = b << 10;
  for (int j = t; j < RPB; j += 256) { cnt[0][j] = 0; cnt[1][j] = 0; cnt[2][j] = 0; }
  __syncthreads();
  int ln = gcount[b];
  const uint2* run = staging + (size_t)b * BCAP;

  // pass A: per-row per-hop counts
  for (int i = t; i < ln; i += 256) {
    uint32_t w = run[i].x;
    int rl = (int)(w >> 22);
    if (w & (1u << 19)) atomicAdd(&cnt[0][rl], 1);
    if (w & (1u << 20)) atomicAdd(&cnt[1][rl], 1);
    if (w & (1u << 21)) atomicAdd(&cnt[2][rl], 1);
  }
  __syncthreads();

  // pass B: evened exclusive scan per hop + global reservation
  for (int h = 0; h < 3; h++) {
    int j0 = t * 4;
    int c0 = cnt[h][j0], c1 = cnt[h][j0 + 1], c2 = cnt[h][j0 + 2], c3 = cnt[h][j0 + 3];
    int e0 = (c0 + 1) & ~1, e1 = (c1 + 1) & ~1, e2 = (c2 + 1) & ~1, e3 = (c3 + 1) & ~1;
    int s4 = e0 + e1 + e2 + e3;
    sm[t] = s4;
    __syncthreads();
    for (int o2 = 1; o2 < 256; o2 <<= 1) {
      int y = (t >= o2) ? sm[t - o2] : 0;
      __syncthreads();
      sm[t] += y;
      __syncthreads();
    }
    int ex = sm[t] - s4;
    off[h][j0]     = ex;
    off[h][j0 + 1] = ex + e0;
    off[h][j0 + 2] = ex + e0 + e1;
    off[h][j0 + 3] = ex + e0 + e1 + e2;
    if (t == 255) gbh[h] = atomicAdd(&gtail[h], sm[255]);
    __syncthreads();
  }

  // pass B2: rowse + pad records + absolute fill positions
  int nr = min(RPB, NTOT - r0);
  for (int h = 0; h < 3; h++) {
    int gb = gbh[h];
    for (int j = t; j < RPB; j += 256) {
      int raw = cnt[h][j];
      int start = gb + off[h][j];
      off[h][j] = start;  // absolute scatter cursor
      if (j < nr) {
        rowse3[h * NTOT + r0 + j] = make_int2(start, start + ((raw + 1) & ~1));
        if (raw & 1) packed3[(size_t)h * HCAP + start + raw] = make_uint2(0u, 0u);
      }
    }
  }
  __syncthreads();

  // pass C: scatter records to per-hop lists
  for (int i = t; i < ln; i += 256) {
    uint2 rec = run[i];
    int rl = (int)(rec.x >> 22);
    uint2 orec = make_uint2(rec.x & COLMASK, rec.y);
    if (rec.x & (1u << 19)) { int p = atomicAdd(&off[0][rl], 1); packed3[0 * (size_t)HCAP + p] = orec; }
    if (rec.x & (1u << 20)) { int p = atomicAdd(&off[1][rl], 1); packed3[1 * (size_t)HCAP + p] = orec; }
    if (rec.x & (1u << 21)) { int p = atomicAdd(&off[2][rl], 1); packed3[2 * (size_t)HCAP + p] = orec; }
  }
}

// ---------------- hop-0: out slot 0 (fp32 NT) + bf16 gather table -----------
__global__ void k_init0(const float* __restrict__ ue, const float* __restrict__ ie,
                        float* __restrict__ out, unsigned short* __restrict__ T0) {
  int t = blockIdx.x * blockDim.x + threadIdx.x;
  if (t >= NTOT * DIM / 4) return;
  int j = t * 4;
  int r = j >> 6;
  int d = j & 63;
  floatx4 v = (r < N_USERS) ? *reinterpret_cast<const floatx4*>(ue + j)
                            : *reinterpret_cast<const floatx4*>(ie + (j - N_USERS * DIM));
  int o = (r < N_USERS) ? (r * 256 + d) : (OUT_I + (r - N_USERS) * 256 + d);
  __builtin_nontemporal_store(v, reinterpret_cast<floatx4*>(out + o));
  ushortx4 bv;
  bv.x = f2bf(v.x); bv.y = f2bf(v.y); bv.z = f2bf(v.z); bv.w = f2bf(v.w);
  *reinterpret_cast<ushortx4*>(T0 + j) = bv;  // cached: gathered by hop 0
}

// ---------------- fused hop: SpMM + LN + dropout + perturb + outputs --------
// one 64-lane wave per row, lane = dim. Gathers read the bf16 table (halved
// bytes + footprint); records via s_load into SGPRs. Writes fp32 outputs and
// the next hop's bf16 table (skipped at the last hop).
template <int HOP>
__global__ __launch_bounds__(256) void k_hop(const int2* __restrict__ rowse,
                                             const uint2* __restrict__ packed,
                                             const unsigned short* __restrict__ Tin,
                                             unsigned short* __restrict__ Tout,
                                             const float* __restrict__ gamma,
                                             const float* __restrict__ beta,
                                             float* __restrict__ out,
                                             uint32_t km0, uint32_t km1,
                                             uint32_t kp0, uint32_t kp1) {
  int lane = threadIdx.x & 63;
  int r = __builtin_amdgcn_readfirstlane((int)(blockIdx.x * blockDim.x + threadIdx.x) >> 6);
  if (r >= NTOT) return;
  int s, e;
  sload_se(rowse + r, s, e);
  s = max(s, 0);
  e = min(e, HCAP);

#define GA(c, vbits, a) {                                                       \
    float xv = __uint_as_float((uint32_t)Tin[(c) * DIM + lane] << 16);          \
    a = fmaf(__uint_as_float(vbits), xv, a); }
  float acc0 = 0.0f, acc1 = 0.0f, acc2 = 0.0f, acc3 = 0.0f;
  int k = s;
  for (; k + 7 < e; k += 8) {
    u32x4 qa, qb, qc, qd;
    sload_rec8(packed + k, qa, qb, qc, qd);
    GA(qa.x, qa.y, acc0) GA(qa.z, qa.w, acc1)
    GA(qb.x, qb.y, acc2) GA(qb.z, qb.w, acc3)
    GA(qc.x, qc.y, acc0) GA(qc.z, qc.w, acc1)
    GA(qd.x, qd.y, acc2) GA(qd.z, qd.w, acc3)
  }
  for (; k + 1 < e; k += 2) {
    u32x4 qa;
    sload_rec2(packed + k, qa);
    GA(qa.x, qa.y, acc0) GA(qa.z, qa.w, acc1)
  }
#undef GA

  float x = (acc0 + acc1) + (acc2 + acc3);

  // layer norm: fused dual reduction (sum, sumsq) over the wave
  float s1 = x, s2 = x * x;
#pragma unroll
  for (int mm = 32; mm >= 1; mm >>= 1) {
    s1 += __shfl_xor(s1, mm, 64);
    s2 += __shfl_xor(s2, mm, 64);
  }
  float mu = s1 * (1.0f / 64.0f);
  float var = fmaxf(s2 * (1.0f / 64.0f) - mu * mu, 0.0f);
  x = (x - mu) * rsqrtf(var + 1e-5f) * gamma[lane] + beta[lane];

  // message dropout: keep iff uniform >= 0.1
  uint32_t j = (uint32_t)(r * DIM + lane);
  float um = u01f(rnd_bits(km0, km1, j));
  const float INV_KEEP = (float)(1.0 / 0.9);
  x = x * ((um >= 0.1f) ? INV_KEEP : 0.0f);

  // perturbation: normal via erfinv of uniform(lo, 1), row-normalized
  float un = u01f(rnd_bits(kp0, kp1, j));
  const float LO = __uint_as_float(0xBF7FFFFFu);  // nextafter(-1, 0)
  float val = un * 2.0f + LO;
  float nz = 0x1.6a09e6p+0f * erfinv_giles(val);   // sqrt(2) * erfinv
  float q2 = nz * nz;
#pragma unroll
  for (int mm = 32; mm >= 1; mm >>= 1) q2 += __shfl_xor(q2, mm, 64);
  float nrm = __builtin_sqrtf(q2);
  float nh = nz / (nrm + 1e-12f);
  float sg = (x > 0.0f) ? 1.0f : ((x < 0.0f) ? -1.0f : 0.0f);
  x = x + sg * nh * 0.03f;

  // next-hop bf16 table (cached; skipped at last hop) + fp32 outputs (NT)
  if (HOP < 2) Tout[r * DIM + lane] = f2bf(x);
  constexpr int h1 = HOP + 1;
  if (r < N_USERS) {
    __builtin_nontemporal_store(x, &out[r * 256 + h1 * 64 + lane]);
    if (HOP == 0) __builtin_nontemporal_store(x, &out[OUT_CLU + r * 64 + lane]);
  } else {
    int i = r - N_USERS;
    __builtin_nontemporal_store(x, &out[OUT_I + i * 256 + h1 * 64 + lane]);
    if (HOP == 0) __builtin_nontemporal_store(x, &out[OUT_CLI + i * 64 + lane]);
  }
}

// ---------------- launch ----------------
extern "C" void kernel_launch(void* const* d_in, const int* in_sizes, int n_in,
                              void* d_out, int out_size, void* d_ws, size_t ws_size,
                              hipStream_t stream) {
  (void)in_sizes; (void)n_in; (void)out_size; (void)ws_size;
  const float* ue    = (const float*)d_in[0];
  const float* ie    = (const float*)d_in[1];
  const float* adjv  = (const float*)d_in[2];
  const float* gamma = (const float*)d_in[3];
  const float* beta  = (const float*)d_in[4];
  const int*   adji  = (const int*)d_in[5];
  const int* rows = adji;
  const int* cols = adji + NNZ;
  float* out = (float*)d_out;

  char* ws = (char*)d_ws;
  size_t off = 0;
  auto alloc = [&](size_t bytes) -> void* {
    void* p = ws + off;
    off += (bytes + 255) & ~(size_t)255;
    return p;
  };
  unsigned short* TA = (unsigned short*)alloc(sizeof(short) * NTOT * DIM);
  unsigned short* TB = (unsigned short*)alloc(sizeof(short) * NTOT * DIM);
  int*   gcount  = (int*)alloc(sizeof(int) * NB);
  int*   gtail   = (int*)alloc(sizeof(int) * 4);
  int2*  rowse3  = (int2*)alloc(sizeof(int2) * 3 * NTOT);
  uint2* staging = (uint2*)alloc(sizeof(uint2) * (size_t)NB * BCAP);
  uint2* packed3 = (uint2*)alloc(sizeof(uint2) * 3 * (size_t)HCAP);

  // host-side key derivation: kh = fold_in(key(42), hop); (ke,km,kp) = split(kh, 3)
  uint32_t K[3][6];
  for (uint32_t h = 0; h < 3; h++) {
    uint32_t h0, h1;
    tf2x32(0u, 42u, 0u, h, h0, h1);
    tf2x32(h0, h1, 0u, 0u, K[h][0], K[h][1]);  // ke
    tf2x32(h0, h1, 0u, 1u, K[h][2], K[h][3]);  // km
    tf2x32(h0, h1, 0u, 2u, K[h][4], K[h][5]);  // kp
  }

  const int nbT = (NNZ + TILE - 1) / TILE;   // 977 tiles
  (void)hipMemsetAsync(gcount, 0, sizeof(int) * NB, stream);
  (void)hipMemsetAsync(gtail, 0, sizeof(int) * 4, stream);

  k_bin<<<nbT, 256, 0, stream>>>(rows, cols, adjv, gcount, staging,
                                 K[0][0], K[0][1], K[1][0], K[1][1],
                                 K[2][0], K[2][1], NNZ);
  k_place3<<<NB, 256, 0, stream>>>(gcount, staging, packed3, rowse3, gtail);
  k_init0<<<(NTOT * DIM / 4 + 255) / 256, 256, 0, stream>>>(ue, ie, out, TA);

  const int nbH = (NTOT * DIM + 255) / 256;
  // hop 0: gather TA, write TB
  k_hop<0><<<nbH, 256, 0, stream>>>(rowse3 + 0 * NTOT, packed3 + 0 * (size_t)HCAP,
                                    TA, TB, gamma, beta, out,
                                    K[0][2], K[0][3], K[0][4], K[0][5]);
  // hop 1: gather TB, write TA
  k_hop<1><<<nbH, 256, 0, stream>>>(rowse3 + 1 * NTOT, packed3 + 1 * (size_t)HCAP,
                                    TB, TA, gamma, beta, out,
                                    K[1][2], K[1][3], K[1][4], K[1][5]);
  // hop 2: gather TA, no table write
  k_hop<2><<<nbH, 256, 0, stream>>>(rowse3 + 2 * NTOT, packed3 + 2 * (size_t)HCAP,
                                    TA, nullptr, gamma, beta, out,
                                    K[2][2], K[2][3], K[2][4], K[2][5]);
}